// Round 4
// baseline (214.783 us; speedup 1.0000x reference)
//
#include <hip/hip_runtime.h>
#include <hip/hip_bf16.h>

#define S_LEN 2048
#define EMB 768
#define NH 12
#define HD 64
#define L2E 1.44269504088896340736f

typedef __attribute__((ext_vector_type(8))) short short8;
typedef __attribute__((ext_vector_type(4))) float f32x4;

typedef __attribute__((address_space(3))) void lds_t;
typedef __attribute__((address_space(1))) const void gbl_t;

__device__ __forceinline__ void gload16(const void* g, void* l) {
  __builtin_amdgcn_global_load_lds((gbl_t*)g, (lds_t*)l, 16, 0, 0);
}

__device__ __forceinline__ short f2bf(float f) {
  union { float f; unsigned u; } v; v.f = f;
  unsigned r = v.u + 0x7FFFu + ((v.u >> 16) & 1u);
  return (short)(r >> 16);
}

__device__ __forceinline__ unsigned pkbf(float a, float b) {
  unsigned r;
  asm("v_cvt_pk_bf16_f32 %0, %1, %2" : "=v"(r) : "v"(a), "v"(b));
  return r;
}

__global__ void cvt_bf16(const float* __restrict__ src, short* __restrict__ dst, int n) {
  int i = (blockIdx.x * blockDim.x + threadIdx.x) * 4;
  if (i >= n) return;
  float4 v = *reinterpret_cast<const float4*>(src + i);
  short4 o;
  o.x = f2bf(v.x); o.y = f2bf(v.y); o.z = f2bf(v.z); o.w = f2bf(v.w);
  *reinterpret_cast<short4*>(dst + i) = o;
}

__global__ void cvt_w(const float* __restrict__ Wq, const float* __restrict__ Wk,
                      const float* __restrict__ Wv, const float* __restrict__ Wo,
                      short* __restrict__ Wb, short* __restrict__ Wob) {
  int sec = blockIdx.y;
  const float* src = sec == 0 ? Wq : sec == 1 ? Wk : sec == 2 ? Wv : Wo;
  short* dst = sec < 3 ? Wb + sec * 589824 : Wob;
  int i = (blockIdx.x * blockDim.x + threadIdx.x) * 4;
  float4 v = *reinterpret_cast<const float4*>(src + i);
  short4 o;
  o.x = f2bf(v.x); o.y = f2bf(v.y); o.z = f2bf(v.z); o.w = f2bf(v.w);
  *reinterpret_cast<short4*>(dst + i) = o;
}

// NT GEMM, m97 structure: global_load_lds width-16 staging, linear LDS [128][64].
template<int MODE>
__global__ __launch_bounds__(256)
void gemm_nt(const short* __restrict__ A, const short* __restrict__ B,
             float* __restrict__ outk, float* __restrict__ outv,
             short* __restrict__ qb, short* __restrict__ kb, short* __restrict__ vtb,
             float* __restrict__ outp, const float* __restrict__ bias) {
  const int K = EMB;
  __shared__ __align__(16) short As[128][64];
  __shared__ __align__(16) short Bs[128][64];
  int tid = threadIdx.x;
  int lane = tid & 63, wid = tid >> 6;
  int wm = wid >> 1, wn = wid & 1;
  int r16 = lane & 15, g4 = lane >> 4;
  int m0 = blockIdx.y * 128, n0 = blockIdx.x * 128;
  int lrow = lane >> 3, lcol = (lane & 7) * 8;   // lane -> (row, col8) within an 8-row slab
  f32x4 acc[4][4] = {};

  for (int k0 = 0; k0 < K; k0 += 64) {
    __syncthreads();  // previous iter's readers done before DMA overwrites
#pragma unroll
    for (int i = 0; i < 4; i++) {
      int r = wid * 32 + i * 8 + lrow;
      gload16(A + (long)(m0 + r) * K + k0 + lcol, &As[r][lcol]);
      gload16(B + (long)(n0 + r) * K + k0 + lcol, &Bs[r][lcol]);
    }
    __syncthreads();  // vmcnt drain: tiles resident
#pragma unroll
    for (int s = 0; s < 2; s++) {
      short8 af[4], bf[4];
#pragma unroll
      for (int t = 0; t < 4; t++) {
        af[t] = *reinterpret_cast<const short8*>(&As[wm * 64 + t * 16 + r16][s * 32 + g4 * 8]);
        bf[t] = *reinterpret_cast<const short8*>(&Bs[wn * 64 + t * 16 + r16][s * 32 + g4 * 8]);
      }
#pragma unroll
      for (int mt = 0; mt < 4; mt++)
#pragma unroll
        for (int nt = 0; nt < 4; nt++)
          acc[mt][nt] = __builtin_amdgcn_mfma_f32_16x16x32_bf16(af[mt], bf[nt], acc[mt][nt], 0, 0, 0);
    }
  }

#pragma unroll
  for (int mt = 0; mt < 4; mt++) {
    int nbase = m0 + wm * 64 + mt * 16 + g4 * 4;
#pragma unroll
    for (int nt = 0; nt < 4; nt++) {
      int f = n0 + wn * 64 + nt * 16 + r16;
#pragma unroll
      for (int r = 0; r < 4; r++) {
        float c = acc[mt][nt][r];
        int nn = nbase + r;
        if (MODE == 0) {
          int b = nn >> 11, s = nn & 2047;
          int sec = f / EMB; int fh = f - sec * EMB;
          int h = fh >> 6, d = fh & 63;
          int idx = (((b * NH) + h) * S_LEN + s) * HD + d;
          if (sec == 0) qb[idx] = f2bf(c);
          else if (sec == 1) { outk[idx] = c; kb[idx] = f2bf(c); }
          else { outv[idx] = c; vtb[(((b * NH) + h) * HD + d) * S_LEN + s] = f2bf(c); }
        } else {
          outp[(long)nn * EMB + f] = c + bias[f];
        }
      }
    }
  }
}

// Flash attention: uniform-work strip pairs + XCD affinity + depth-1 K/V prefetch.
// Grid 768: id&7 = XCD; 96 blocks/XCD = 3 bh x 32 pairs. Block does strips
// {63-p, p} sequentially (65 tiles total -> uniform). 4 waves split each strip.
__global__ __launch_bounds__(256, 3)
void flash_attn4(const short* __restrict__ qb, const short* __restrict__ kb,
                 const short* __restrict__ vtb, short* __restrict__ mb) {
  const int tid = threadIdx.x;
  const int w = tid >> 6, lane = tid & 63;
  const int r16 = lane & 15, g4 = lane >> 4;
  const int id = blockIdx.x;
  const int xcd = id & 7, j = id >> 3;
  const int bh = xcd + 8 * (j >> 5);
  const int pair = j & 31;

  const short* qh = qb + (long)bh * S_LEN * HD;
  const short* kh = kb + (long)bh * S_LEN * HD;
  const short* vh = vtb + (long)bh * HD * S_LEN;

  __shared__ __align__(16) short P_lds[4][32][40];
  __shared__ __align__(16) float sca_lds[4][32];
  __shared__ float mlm[4][32], mll[4][32];
  __shared__ __align__(16) float wsc[4][32];
  __shared__ __align__(16) float o_lds[32][68];
  __shared__ float l_red[32];

  for (int half = 0; half < 2; half++) {
    const int strip = half == 0 ? (63 - pair) : pair;
    const int q0 = strip * 32;
    const int nkt = strip + 1;
    const int diag_kr0 = (nkt - 1) * 32;

    __syncthreads();  // o_lds from previous half fully consumed
    for (int i = tid; i < 32 * 68; i += 256) (&o_lds[0][0])[i] = 0.f;

    short8 qf[2][2];
#pragma unroll
    for (int ct = 0; ct < 2; ct++)
#pragma unroll
      for (int ksl = 0; ksl < 2; ksl++)
        qf[ct][ksl] = *reinterpret_cast<const short8*>(qh + (q0 + ct * 16 + r16) * HD + ksl * 32 + g4 * 8);

    float m[2]  = {-1e30f, -1e30f};
    float m2[2] = {-1.44e30f, -1.44e30f};
    float l[2]  = {0.f, 0.f};
    f32x4 oacc[2][4] = {};

    int base = nkt >> 2, rem = nkt & 3;
    int start = w * base + (w < rem ? w : rem);
    int count = base + (w < rem ? 1 : 0);

    auto loadt = [&](short8 (&kf)[2][2], short8 (&vf)[4], int kr0) {
#pragma unroll
      for (int mt = 0; mt < 2; mt++)
#pragma unroll
        for (int ksl = 0; ksl < 2; ksl++)
          kf[mt][ksl] = *reinterpret_cast<const short8*>(kh + (kr0 + mt * 16 + r16) * HD + ksl * 32 + g4 * 8);
#pragma unroll
      for (int dt = 0; dt < 4; dt++)
        vf[dt] = *reinterpret_cast<const short8*>(vh + (dt * 16 + r16) * S_LEN + kr0 + g4 * 8);
    };

    auto compute = [&](short8 (&kf)[2][2], short8 (&vf)[4], int kr0) {
      f32x4 sc[2][2] = {};
#pragma unroll
      for (int mt = 0; mt < 2; mt++)
#pragma unroll
        for (int ct = 0; ct < 2; ct++) {
          sc[mt][ct] = __builtin_amdgcn_mfma_f32_16x16x32_bf16(kf[mt][0], qf[ct][0], sc[mt][ct], 0, 0, 0);
          sc[mt][ct] = __builtin_amdgcn_mfma_f32_16x16x32_bf16(kf[mt][1], qf[ct][1], sc[mt][ct], 0, 0, 0);
        }

      if (kr0 == diag_kr0) {  // diagonal tile: mask k > q
#pragma unroll
        for (int mt = 0; mt < 2; mt++)
#pragma unroll
          for (int ct = 0; ct < 2; ct++)
#pragma unroll
            for (int r = 0; r < 4; r++)
              if (mt * 16 + g4 * 4 + r > ct * 16 + r16) sc[mt][ct][r] = -1e30f;
      }

      float rm[2];
#pragma unroll
      for (int ct = 0; ct < 2; ct++) {
        float a = fmaxf(fmaxf(sc[0][ct][0], sc[0][ct][1]), fmaxf(sc[0][ct][2], sc[0][ct][3]));
        float b = fmaxf(fmaxf(sc[1][ct][0], sc[1][ct][1]), fmaxf(sc[1][ct][2], sc[1][ct][3]));
        float x = fmaxf(a, b);
        x = fmaxf(x, __shfl_xor(x, 16));
        x = fmaxf(x, __shfl_xor(x, 32));
        rm[ct] = x;
      }

      bool cond = (rm[0] <= m[0] + 8.f) && (rm[1] <= m[1] + 8.f);
      if (!__all(cond)) {
        float sca[2];
#pragma unroll
        for (int ct = 0; ct < 2; ct++) {
          float nm = fmaxf(m[ct], rm[ct]);
          sca[ct] = __builtin_exp2f((m[ct] - nm) * L2E);
          m[ct] = nm; m2[ct] = nm * L2E;
          l[ct] *= sca[ct];
        }
        if (g4 == 0) { sca_lds[w][r16] = sca[0]; sca_lds[w][16 + r16] = sca[1]; }
        f32x4 sr[2];
#pragma unroll
        for (int mt = 0; mt < 2; mt++)
          sr[mt] = *reinterpret_cast<const f32x4*>(&sca_lds[w][mt * 16 + g4 * 4]);
#pragma unroll
        for (int mt = 0; mt < 2; mt++)
#pragma unroll
          for (int dt = 0; dt < 4; dt++)
#pragma unroll
            for (int r = 0; r < 4; r++) oacc[mt][dt][r] *= sr[mt][r];
      }

      float p[2][2][4];
      float rs[2] = {0.f, 0.f};
#pragma unroll
      for (int mt = 0; mt < 2; mt++)
#pragma unroll
        for (int ct = 0; ct < 2; ct++)
#pragma unroll
          for (int r = 0; r < 4; r++) {
            float e = __builtin_exp2f(fmaf(sc[mt][ct][r], L2E, -m2[ct]));
            p[mt][ct][r] = e;
            rs[ct] += e;
          }
#pragma unroll
      for (int ct = 0; ct < 2; ct++) {
        float x = rs[ct];
        x += __shfl_xor(x, 16);
        x += __shfl_xor(x, 32);
        l[ct] += x;
      }
#pragma unroll
      for (int mt = 0; mt < 2; mt++)
#pragma unroll
        for (int ct = 0; ct < 2; ct++) {
          uint2 wv;
          wv.x = pkbf(p[mt][ct][0], p[mt][ct][1]);
          wv.y = pkbf(p[mt][ct][2], p[mt][ct][3]);
          *reinterpret_cast<uint2*>(&P_lds[w][ct * 16 + r16][mt * 16 + g4 * 4]) = wv;
        }

      short8 pa[2];
#pragma unroll
      for (int mt = 0; mt < 2; mt++)
        pa[mt] = *reinterpret_cast<const short8*>(&P_lds[w][mt * 16 + r16][g4 * 8]);
#pragma unroll
      for (int dt = 0; dt < 4; dt++)
#pragma unroll
        for (int mt = 0; mt < 2; mt++)
          oacc[mt][dt] = __builtin_amdgcn_mfma_f32_16x16x32_bf16(pa[mt], vf[dt], oacc[mt][dt], 0, 0, 0);
    };

    short8 kfA[2][2], vfA[4], kfB[2][2], vfB[4];
    if (count > 0) loadt(kfA, vfA, start * 32);
    int it = 0;
    for (; it + 2 <= count; it += 2) {
      loadt(kfB, vfB, (start + it + 1) * 32);
      compute(kfA, vfA, (start + it) * 32);
      if (it + 3 <= count) loadt(kfA, vfA, (start + it + 2) * 32);
      compute(kfB, vfB, (start + it + 1) * 32);
    }
    if (it < count) compute(kfA, vfA, (start + it) * 32);

    // ---- block merge across the 4 KV-chunk waves ----
    if (g4 == 0) {
      mlm[w][r16] = m[0]; mll[w][r16] = l[0];
      mlm[w][16 + r16] = m[1]; mll[w][16 + r16] = l[1];
    }
    __syncthreads();
    if (tid < 32) {
      float M = fmaxf(fmaxf(mlm[0][tid], mlm[1][tid]), fmaxf(mlm[2][tid], mlm[3][tid]));
      float Ls = 0.f;
#pragma unroll
      for (int ww = 0; ww < 4; ww++) {
        float e = __builtin_exp2f((mlm[ww][tid] - M) * L2E);
        wsc[ww][tid] = e;
        Ls += e * mll[ww][tid];
      }
      l_red[tid] = Ls;
    }
    __syncthreads();
    {
      f32x4 fw[2];
#pragma unroll
      for (int mt = 0; mt < 2; mt++)
        fw[mt] = *reinterpret_cast<const f32x4*>(&wsc[w][mt * 16 + g4 * 4]);
#pragma unroll
      for (int mt = 0; mt < 2; mt++)
#pragma unroll
        for (int dt = 0; dt < 4; dt++)
#pragma unroll
          for (int r = 0; r < 4; r++)
            atomicAdd(&o_lds[mt * 16 + g4 * 4 + r][dt * 16 + r16], oacc[mt][dt][r] * fw[mt][r]);
    }
    __syncthreads();
    {
      int q = tid >> 3, db = (tid & 7) * 8;
      float inv = 1.f / l_red[q];
      f32x4 a = *reinterpret_cast<const f32x4*>(&o_lds[q][db]);
      f32x4 b = *reinterpret_cast<const f32x4*>(&o_lds[q][db + 4]);
      short8 o8;
#pragma unroll
      for (int jj = 0; jj < 4; jj++) { o8[jj] = f2bf(a[jj] * inv); o8[4 + jj] = f2bf(b[jj] * inv); }
      int bb = bh / NH, h = bh % NH;
      *reinterpret_cast<short8*>(&mb[((long)(bb * S_LEN + q0 + q)) * EMB + h * HD + db]) = o8;
    }
  }
}

extern "C" void kernel_launch(void* const* d_in, const int* in_sizes, int n_in,
                              void* d_out, int out_size, void* d_ws, size_t ws_size,
                              hipStream_t stream) {
  const float* x  = (const float*)d_in[0];
  const float* Wq = (const float*)d_in[1];
  const float* Wk = (const float*)d_in[2];
  const float* Wv = (const float*)d_in[3];
  const float* Wo = (const float*)d_in[4];
  const float* bo = (const float*)d_in[5];

  float* out  = (float*)d_out;
  float* outk = out + 3145728;
  float* outv = out + 6291456;

  short* ws  = (short*)d_ws;
  short* xb  = ws;                 // [4096][768]
  short* Wb  = xb + 3145728;       // [2304][768]  (Wq;Wk;Wv)
  short* Wob = Wb + 1769472;       // [768][768]
  short* qb  = Wob + 589824;       // [24][2048][64]
  short* kb  = qb + 3145728;       // [24][2048][64]
  short* vtb = kb + 3145728;       // [24][64][2048]  (V transposed per head)
  short* mb  = vtb + 3145728;      // [4096][768]    merged attn, bf16

  cvt_bf16<<<3072, 256, 0, stream>>>(x, xb, 3145728);
  cvt_w<<<dim3(576, 4), 256, 0, stream>>>(Wq, Wk, Wv, Wo, Wb, Wob);

  gemm_nt<0><<<dim3(18, 32), 256, 0, stream>>>(xb, Wb, outk, outv, qb, kb, vtb, nullptr, nullptr);
  flash_attn4<<<768, 256, 0, stream>>>(qb, kb, vtb, mb);
  gemm_nt<1><<<dim3(6, 32), 256, 0, stream>>>(mb, Wob, nullptr, nullptr, nullptr, nullptr, nullptr, out, bo);
}

// Round 5
// 200.296 us; speedup vs baseline: 1.0723x; 1.0723x over previous
//
#include <hip/hip_runtime.h>
#include <hip/hip_bf16.h>

#define S_LEN 2048
#define EMB 768
#define NH 12
#define HD 64
#define L2E 1.44269504088896340736f

typedef __attribute__((ext_vector_type(8))) short short8;
typedef __attribute__((ext_vector_type(4))) float f32x4;

typedef __attribute__((address_space(3))) void lds_t;
typedef __attribute__((address_space(1))) const void gbl_t;

__device__ __forceinline__ void gload16(const void* g, void* l) {
  __builtin_amdgcn_global_load_lds((gbl_t*)g, (lds_t*)l, 16, 0, 0);
}

__device__ __forceinline__ short f2bf(float f) {
  union { float f; unsigned u; } v; v.f = f;
  unsigned r = v.u + 0x7FFFu + ((v.u >> 16) & 1u);
  return (short)(r >> 16);
}

__device__ __forceinline__ unsigned pkbf(float a, float b) {
  unsigned r;
  asm("v_cvt_pk_bf16_f32 %0, %1, %2" : "=v"(r) : "v"(a), "v"(b));
  return r;
}

__global__ void cvt_bf16(const float* __restrict__ src, short* __restrict__ dst, int n) {
  int i = (blockIdx.x * blockDim.x + threadIdx.x) * 4;
  if (i >= n) return;
  float4 v = *reinterpret_cast<const float4*>(src + i);
  short4 o;
  o.x = f2bf(v.x); o.y = f2bf(v.y); o.z = f2bf(v.z); o.w = f2bf(v.w);
  *reinterpret_cast<short4*>(dst + i) = o;
}

__global__ void cvt_w(const float* __restrict__ Wq, const float* __restrict__ Wk,
                      const float* __restrict__ Wv, const float* __restrict__ Wo,
                      short* __restrict__ Wb, short* __restrict__ Wob) {
  int sec = blockIdx.y;
  const float* src = sec == 0 ? Wq : sec == 1 ? Wk : sec == 2 ? Wv : Wo;
  short* dst = sec < 3 ? Wb + sec * 589824 : Wob;
  int i = (blockIdx.x * blockDim.x + threadIdx.x) * 4;
  float4 v = *reinterpret_cast<const float4*>(src + i);
  short4 o;
  o.x = f2bf(v.x); o.y = f2bf(v.y); o.z = f2bf(v.z); o.w = f2bf(v.w);
  *reinterpret_cast<short4*>(dst + i) = o;
}

// NT GEMM, 2-phase double-buffered global_load_lds staging.
// Per K-step: barrier (drains prev STAGE) -> issue STAGE(next) -> compute(cur).
template<int MODE>
__global__ __launch_bounds__(256)
void gemm_nt(const short* __restrict__ A, const short* __restrict__ B,
             float* __restrict__ outk, float* __restrict__ outv,
             short* __restrict__ qb, short* __restrict__ kb, short* __restrict__ vtb,
             float* __restrict__ outp, const float* __restrict__ bias) {
  const int K = EMB;
  __shared__ __align__(16) short As[2][128][64];
  __shared__ __align__(16) short Bs[2][128][64];
  int tid = threadIdx.x;
  int lane = tid & 63, wid = tid >> 6;
  int wm = wid >> 1, wn = wid & 1;
  int r16 = lane & 15, g4 = lane >> 4;
  int m0 = blockIdx.y * 128, n0 = blockIdx.x * 128;
  int lrow = lane >> 3, lcol = (lane & 7) * 8;  // lane*16B linear within 8-row slab
  f32x4 acc[4][4] = {};

#define STAGE(BUF, K0) do {                                          \
    _Pragma("unroll")                                                \
    for (int i = 0; i < 4; i++) {                                    \
      int r = wid * 32 + i * 8 + lrow;                               \
      gload16(A + (long)(m0 + r) * K + (K0) + lcol, &As[BUF][r][lcol]); \
      gload16(B + (long)(n0 + r) * K + (K0) + lcol, &Bs[BUF][r][lcol]); \
    } } while (0)

  STAGE(0, 0);
  int cur = 0;
  for (int t = 0; t < K / 64; t++) {
    __syncthreads();  // drains vmcnt: buf[cur] resident; prev readers done
    if (t + 1 < K / 64) STAGE(cur ^ 1, (t + 1) * 64);
#pragma unroll
    for (int s = 0; s < 2; s++) {
      short8 af[4], bf[4];
#pragma unroll
      for (int tt = 0; tt < 4; tt++) {
        af[tt] = *reinterpret_cast<const short8*>(&As[cur][wm * 64 + tt * 16 + r16][s * 32 + g4 * 8]);
        bf[tt] = *reinterpret_cast<const short8*>(&Bs[cur][wn * 64 + tt * 16 + r16][s * 32 + g4 * 8]);
      }
#pragma unroll
      for (int mt = 0; mt < 4; mt++)
#pragma unroll
        for (int nt = 0; nt < 4; nt++)
          acc[mt][nt] = __builtin_amdgcn_mfma_f32_16x16x32_bf16(af[mt], bf[nt], acc[mt][nt], 0, 0, 0);
    }
    cur ^= 1;
  }
#undef STAGE

#pragma unroll
  for (int mt = 0; mt < 4; mt++) {
    int nbase = m0 + wm * 64 + mt * 16 + g4 * 4;
#pragma unroll
    for (int nt = 0; nt < 4; nt++) {
      int f = n0 + wn * 64 + nt * 16 + r16;
#pragma unroll
      for (int r = 0; r < 4; r++) {
        float c = acc[mt][nt][r];
        int nn = nbase + r;
        if (MODE == 0) {
          int b = nn >> 11, s = nn & 2047;
          int sec = f / EMB; int fh = f - sec * EMB;
          int h = fh >> 6, d = fh & 63;
          int idx = (((b * NH) + h) * S_LEN + s) * HD + d;
          if (sec == 0) qb[idx] = f2bf(c);
          else if (sec == 1) { outk[idx] = c; kb[idx] = f2bf(c); }
          else { outv[idx] = c; vtb[(((b * NH) + h) * HD + d) * S_LEN + s] = f2bf(c); }
        } else {
          outp[(long)nn * EMB + f] = c + bias[f];
        }
      }
    }
  }
}

// Flash attention: uniform strip pairs + XCD affinity + register double-buffered
// K/V prefetch with fully-named registers (no arrays/lambdas -> no scratch).
__global__ __launch_bounds__(256, 3)
void flash_attn5(const short* __restrict__ qb, const short* __restrict__ kb,
                 const short* __restrict__ vtb, short* __restrict__ mb) {
  const int tid = threadIdx.x;
  const int w = tid >> 6, lane = tid & 63;
  const int r16 = lane & 15, g4 = lane >> 4;
  const int id = blockIdx.x;
  const int xcd = id & 7, j = id >> 3;
  const int bh = xcd + 8 * (j >> 5);
  const int pair = j & 31;

  const short* qh = qb + (long)bh * S_LEN * HD;
  const short* kh = kb + (long)bh * S_LEN * HD;
  const short* vh = vtb + (long)bh * HD * S_LEN;

  __shared__ __align__(16) short P_lds[4][32][40];
  __shared__ __align__(16) float sca_lds[4][32];
  __shared__ float mlm[4][32], mll[4][32];
  __shared__ __align__(16) float wsc[4][32];
  __shared__ __align__(16) float o_lds[32][68];
  __shared__ float l_red[32];

#define ISSUE(KP, VP, KR0) do {                                      \
    const short* _kp = kh + ((KR0) + r16) * HD + g4 * 8;             \
    KP##0 = *reinterpret_cast<const short8*>(_kp);                   \
    KP##1 = *reinterpret_cast<const short8*>(_kp + 32);              \
    KP##2 = *reinterpret_cast<const short8*>(_kp + 16 * HD);         \
    KP##3 = *reinterpret_cast<const short8*>(_kp + 16 * HD + 32);    \
    const short* _vp = vh + r16 * S_LEN + (KR0) + g4 * 8;            \
    VP##0 = *reinterpret_cast<const short8*>(_vp);                   \
    VP##1 = *reinterpret_cast<const short8*>(_vp + 16 * S_LEN);      \
    VP##2 = *reinterpret_cast<const short8*>(_vp + 32 * S_LEN);      \
    VP##3 = *reinterpret_cast<const short8*>(_vp + 48 * S_LEN);      \
  } while (0)

// sNM: N = k-block (mt), M = q-block (ct). k-row = mt*16+g4*4+r, q-col = ct*16+r16.
#define BODY(KP, VP, NK, NV, KR0, DONEXT, KR0N) do {                                   \
    const int _k0 = (KR0);                                                             \
    f32x4 s00 = {0.f,0.f,0.f,0.f}, s01 = {0.f,0.f,0.f,0.f};                            \
    f32x4 s10 = {0.f,0.f,0.f,0.f}, s11 = {0.f,0.f,0.f,0.f};                            \
    s00 = __builtin_amdgcn_mfma_f32_16x16x32_bf16(KP##0, qf00, s00, 0, 0, 0);          \
    s00 = __builtin_amdgcn_mfma_f32_16x16x32_bf16(KP##1, qf01, s00, 0, 0, 0);          \
    s10 = __builtin_amdgcn_mfma_f32_16x16x32_bf16(KP##2, qf00, s10, 0, 0, 0);          \
    s10 = __builtin_amdgcn_mfma_f32_16x16x32_bf16(KP##3, qf01, s10, 0, 0, 0);          \
    s01 = __builtin_amdgcn_mfma_f32_16x16x32_bf16(KP##0, qf10, s01, 0, 0, 0);          \
    s01 = __builtin_amdgcn_mfma_f32_16x16x32_bf16(KP##1, qf11, s01, 0, 0, 0);          \
    s11 = __builtin_amdgcn_mfma_f32_16x16x32_bf16(KP##2, qf10, s11, 0, 0, 0);          \
    s11 = __builtin_amdgcn_mfma_f32_16x16x32_bf16(KP##3, qf11, s11, 0, 0, 0);          \
    if (DONEXT) { ISSUE(NK, NV, (KR0N)); }                                             \
    if (_k0 == diag_kr0) {                                                             \
      _Pragma("unroll")                                                                \
      for (int r = 0; r < 4; r++) {                                                    \
        if (g4 * 4 + r > r16)           s00[r] = -1e30f;                               \
        if (16 + g4 * 4 + r > r16)      s10[r] = -1e30f;                               \
        if (g4 * 4 + r > 16 + r16)      s01[r] = -1e30f;                               \
        if (16 + g4 * 4 + r > 16 + r16) s11[r] = -1e30f;                               \
      }                                                                                \
    }                                                                                  \
    float rm0, rm1;                                                                    \
    {                                                                                  \
      float a = fmaxf(fmaxf(s00[0], s00[1]), fmaxf(s00[2], s00[3]));                   \
      float b = fmaxf(fmaxf(s10[0], s10[1]), fmaxf(s10[2], s10[3]));                   \
      float x = fmaxf(a, b);                                                           \
      x = fmaxf(x, __shfl_xor(x, 16)); x = fmaxf(x, __shfl_xor(x, 32));                \
      rm0 = x;                                                                         \
      a = fmaxf(fmaxf(s01[0], s01[1]), fmaxf(s01[2], s01[3]));                         \
      b = fmaxf(fmaxf(s11[0], s11[1]), fmaxf(s11[2], s11[3]));                         \
      x = fmaxf(a, b);                                                                 \
      x = fmaxf(x, __shfl_xor(x, 16)); x = fmaxf(x, __shfl_xor(x, 32));                \
      rm1 = x;                                                                         \
    }                                                                                  \
    bool cond = (rm0 <= m0 + 8.f) && (rm1 <= m1 + 8.f);                                \
    if (!__all(cond)) {                                                                \
      float nm0 = fmaxf(m0, rm0), nm1 = fmaxf(m1, rm1);                                \
      float sca0 = __builtin_exp2f((m0 - nm0) * L2E);                                  \
      float sca1 = __builtin_exp2f((m1 - nm1) * L2E);                                  \
      m0 = nm0; m20 = nm0 * L2E; l0 *= sca0;                                           \
      m1 = nm1; m21 = nm1 * L2E; l1 *= sca1;                                           \
      if (g4 == 0) { sca_lds[w][r16] = sca0; sca_lds[w][16 + r16] = sca1; }            \
      f32x4 sr0 = *reinterpret_cast<const f32x4*>(&sca_lds[w][g4 * 4]);                \
      f32x4 sr1 = *reinterpret_cast<const f32x4*>(&sca_lds[w][16 + g4 * 4]);           \
      _Pragma("unroll")                                                                \
      for (int dt = 0; dt < 4; dt++)                                                   \
        _Pragma("unroll")                                                              \
        for (int r = 0; r < 4; r++) {                                                  \
          oacc[0][dt][r] *= sr0[r]; oacc[1][dt][r] *= sr1[r];                          \
        }                                                                              \
    }                                                                                  \
    float rs0 = 0.f, rs1 = 0.f;                                                        \
    _Pragma("unroll")                                                                  \
    for (int r = 0; r < 4; r++) {                                                      \
      s00[r] = __builtin_exp2f(fmaf(s00[r], L2E, -m20));                               \
      s10[r] = __builtin_exp2f(fmaf(s10[r], L2E, -m20));                               \
      s01[r] = __builtin_exp2f(fmaf(s01[r], L2E, -m21));                               \
      s11[r] = __builtin_exp2f(fmaf(s11[r], L2E, -m21));                               \
      rs0 += s00[r] + s10[r]; rs1 += s01[r] + s11[r];                                  \
    }                                                                                  \
    rs0 += __shfl_xor(rs0, 16); rs0 += __shfl_xor(rs0, 32);                            \
    rs1 += __shfl_xor(rs1, 16); rs1 += __shfl_xor(rs1, 32);                            \
    l0 += rs0; l1 += rs1;                                                              \
    {                                                                                  \
      uint2 wv;                                                                        \
      wv.x = pkbf(s00[0], s00[1]); wv.y = pkbf(s00[2], s00[3]);                        \
      *reinterpret_cast<uint2*>(&P_lds[w][r16][g4 * 4]) = wv;                          \
      wv.x = pkbf(s10[0], s10[1]); wv.y = pkbf(s10[2], s10[3]);                        \
      *reinterpret_cast<uint2*>(&P_lds[w][r16][16 + g4 * 4]) = wv;                     \
      wv.x = pkbf(s01[0], s01[1]); wv.y = pkbf(s01[2], s01[3]);                        \
      *reinterpret_cast<uint2*>(&P_lds[w][16 + r16][g4 * 4]) = wv;                     \
      wv.x = pkbf(s11[0], s11[1]); wv.y = pkbf(s11[2], s11[3]);                        \
      *reinterpret_cast<uint2*>(&P_lds[w][16 + r16][16 + g4 * 4]) = wv;                \
    }                                                                                  \
    short8 pa0 = *reinterpret_cast<const short8*>(&P_lds[w][r16][g4 * 8]);             \
    short8 pa1 = *reinterpret_cast<const short8*>(&P_lds[w][16 + r16][g4 * 8]);        \
    oacc[0][0] = __builtin_amdgcn_mfma_f32_16x16x32_bf16(pa0, VP##0, oacc[0][0], 0, 0, 0); \
    oacc[1][0] = __builtin_amdgcn_mfma_f32_16x16x32_bf16(pa1, VP##0, oacc[1][0], 0, 0, 0); \
    oacc[0][1] = __builtin_amdgcn_mfma_f32_16x16x32_bf16(pa0, VP##1, oacc[0][1], 0, 0, 0); \
    oacc[1][1] = __builtin_amdgcn_mfma_f32_16x16x32_bf16(pa1, VP##1, oacc[1][1], 0, 0, 0); \
    oacc[0][2] = __builtin_amdgcn_mfma_f32_16x16x32_bf16(pa0, VP##2, oacc[0][2], 0, 0, 0); \
    oacc[1][2] = __builtin_amdgcn_mfma_f32_16x16x32_bf16(pa1, VP##2, oacc[1][2], 0, 0, 0); \
    oacc[0][3] = __builtin_amdgcn_mfma_f32_16x16x32_bf16(pa0, VP##3, oacc[0][3], 0, 0, 0); \
    oacc[1][3] = __builtin_amdgcn_mfma_f32_16x16x32_bf16(pa1, VP##3, oacc[1][3], 0, 0, 0); \
  } while (0)

  for (int half = 0; half < 2; half++) {
    const int strip = half == 0 ? (63 - pair) : pair;
    const int q0 = strip * 32;
    const int nkt = strip + 1;
    const int diag_kr0 = (nkt - 1) * 32;

    __syncthreads();  // o_lds from previous half fully consumed
    for (int i = tid; i < 32 * 68; i += 256) (&o_lds[0][0])[i] = 0.f;

    short8 qf00 = *reinterpret_cast<const short8*>(qh + (q0 + r16) * HD + g4 * 8);
    short8 qf01 = *reinterpret_cast<const short8*>(qh + (q0 + r16) * HD + 32 + g4 * 8);
    short8 qf10 = *reinterpret_cast<const short8*>(qh + (q0 + 16 + r16) * HD + g4 * 8);
    short8 qf11 = *reinterpret_cast<const short8*>(qh + (q0 + 16 + r16) * HD + 32 + g4 * 8);

    float m0 = -1e30f, m1 = -1e30f;
    float m20 = -1.44e30f, m21 = -1.44e30f;
    float l0 = 0.f, l1 = 0.f;
    f32x4 oacc[2][4] = {};

    int base = nkt >> 2, rem = nkt & 3;
    int start = w * base + (w < rem ? w : rem);
    int count = base + (w < rem ? 1 : 0);

    short8 kA0, kA1, kA2, kA3, vA0, vA1, vA2, vA3;
    short8 kB0, kB1, kB2, kB3, vB0, vB1, vB2, vB3;
    if (count > 0) ISSUE(kA, vA, start * 32);
    int it = 0;
    for (; it + 2 <= count; it += 2) {
      BODY(kA, vA, kB, vB, (start + it) * 32, true, (start + it + 1) * 32);
      BODY(kB, vB, kA, vA, (start + it + 1) * 32, it + 3 <= count, (start + it + 2) * 32);
    }
    if (it < count) BODY(kA, vA, kB, vB, (start + it) * 32, false, 0);

    // ---- block merge across the 4 KV-chunk waves ----
    if (g4 == 0) {
      mlm[w][r16] = m0; mll[w][r16] = l0;
      mlm[w][16 + r16] = m1; mll[w][16 + r16] = l1;
    }
    __syncthreads();
    if (tid < 32) {
      float M = fmaxf(fmaxf(mlm[0][tid], mlm[1][tid]), fmaxf(mlm[2][tid], mlm[3][tid]));
      float Ls = 0.f;
#pragma unroll
      for (int ww = 0; ww < 4; ww++) {
        float e = __builtin_exp2f((mlm[ww][tid] - M) * L2E);
        wsc[ww][tid] = e;
        Ls += e * mll[ww][tid];
      }
      l_red[tid] = Ls;
    }
    __syncthreads();
    {
      f32x4 fw0 = *reinterpret_cast<const f32x4*>(&wsc[w][g4 * 4]);
      f32x4 fw1 = *reinterpret_cast<const f32x4*>(&wsc[w][16 + g4 * 4]);
#pragma unroll
      for (int dt = 0; dt < 4; dt++)
#pragma unroll
        for (int r = 0; r < 4; r++) {
          atomicAdd(&o_lds[g4 * 4 + r][dt * 16 + r16], oacc[0][dt][r] * fw0[r]);
          atomicAdd(&o_lds[16 + g4 * 4 + r][dt * 16 + r16], oacc[1][dt][r] * fw1[r]);
        }
    }
    __syncthreads();
    {
      int q = tid >> 3, db = (tid & 7) * 8;
      float inv = 1.f / l_red[q];
      f32x4 a = *reinterpret_cast<const f32x4*>(&o_lds[q][db]);
      f32x4 b = *reinterpret_cast<const f32x4*>(&o_lds[q][db + 4]);
      short8 o8;
#pragma unroll
      for (int jj = 0; jj < 4; jj++) { o8[jj] = f2bf(a[jj] * inv); o8[4 + jj] = f2bf(b[jj] * inv); }
      int bb = bh / NH, h = bh % NH;
      *reinterpret_cast<short8*>(&mb[((long)(bb * S_LEN + q0 + q)) * EMB + h * HD + db]) = o8;
    }
  }
#undef BODY
#undef ISSUE
}

extern "C" void kernel_launch(void* const* d_in, const int* in_sizes, int n_in,
                              void* d_out, int out_size, void* d_ws, size_t ws_size,
                              hipStream_t stream) {
  const float* x  = (const float*)d_in[0];
  const float* Wq = (const float*)d_in[1];
  const float* Wk = (const float*)d_in[2];
  const float* Wv = (const float*)d_in[3];
  const float* Wo = (const float*)d_in[4];
  const float* bo = (const float*)d_in[5];

  float* out  = (float*)d_out;
  float* outk = out + 3145728;
  float* outv = out + 6291456;

  short* ws  = (short*)d_ws;
  short* xb  = ws;                 // [4096][768]
  short* Wb  = xb + 3145728;       // [2304][768]  (Wq;Wk;Wv)
  short* Wob = Wb + 1769472;       // [768][768]
  short* qb  = Wob + 589824;       // [24][2048][64]
  short* kb  = qb + 3145728;       // [24][2048][64]
  short* vtb = kb + 3145728;       // [24][64][2048]  (V transposed per head)
  short* mb  = vtb + 3145728;      // [4096][768]    merged attn, bf16

  cvt_bf16<<<3072, 256, 0, stream>>>(x, xb, 3145728);
  cvt_w<<<dim3(576, 4), 256, 0, stream>>>(Wq, Wk, Wv, Wo, Wb, Wob);

  gemm_nt<0><<<dim3(18, 32), 256, 0, stream>>>(xb, Wb, outk, outv, qb, kb, vtb, nullptr, nullptr);
  flash_attn5<<<768, 256, 0, stream>>>(qb, kb, vtb, mb);
  gemm_nt<1><<<dim3(6, 32), 256, 0, stream>>>(mb, Wob, nullptr, nullptr, nullptr, nullptr, nullptr, out, bo);
}

// Round 6
// 195.628 us; speedup vs baseline: 1.0979x; 1.0239x over previous
//
#include <hip/hip_runtime.h>
#include <hip/hip_bf16.h>

#define S_LEN 2048
#define EMB 768
#define NH 12
#define HD 64
#define L2E 1.44269504088896340736f

typedef __attribute__((ext_vector_type(8))) short short8;
typedef __attribute__((ext_vector_type(4))) float f32x4;

typedef __attribute__((address_space(3))) void lds_t;
typedef __attribute__((address_space(1))) const void gbl_t;

__device__ __forceinline__ void gload16(const void* g, void* l) {
  __builtin_amdgcn_global_load_lds((gbl_t*)g, (lds_t*)l, 16, 0, 0);
}

__device__ __forceinline__ short f2bf(float f) {
  union { float f; unsigned u; } v; v.f = f;
  unsigned r = v.u + 0x7FFFu + ((v.u >> 16) & 1u);
  return (short)(r >> 16);
}

__device__ __forceinline__ unsigned pkbf(float a, float b) {
  unsigned r;
  asm("v_cvt_pk_bf16_f32 %0, %1, %2" : "=v"(r) : "v"(a), "v"(b));
  return r;
}

__global__ void cvt_bf16(const float* __restrict__ src, short* __restrict__ dst, int n) {
  int i = (blockIdx.x * blockDim.x + threadIdx.x) * 4;
  if (i >= n) return;
  float4 v = *reinterpret_cast<const float4*>(src + i);
  short4 o;
  o.x = f2bf(v.x); o.y = f2bf(v.y); o.z = f2bf(v.z); o.w = f2bf(v.w);
  *reinterpret_cast<short4*>(dst + i) = o;
}

__global__ void cvt_w(const float* __restrict__ Wq, const float* __restrict__ Wk,
                      const float* __restrict__ Wv, const float* __restrict__ Wo,
                      short* __restrict__ Wb, short* __restrict__ Wob) {
  int sec = blockIdx.y;
  const float* src = sec == 0 ? Wq : sec == 1 ? Wk : sec == 2 ? Wv : Wo;
  short* dst = sec < 3 ? Wb + sec * 589824 : Wob;
  int i = (blockIdx.x * blockDim.x + threadIdx.x) * 4;
  float4 v = *reinterpret_cast<const float4*>(src + i);
  short4 o;
  o.x = f2bf(v.x); o.y = f2bf(v.y); o.z = f2bf(v.z); o.w = f2bf(v.w);
  *reinterpret_cast<short4*>(dst + i) = o;
}

// NT GEMM, 2-phase double-buffered global_load_lds staging.
template<int MODE>
__global__ __launch_bounds__(256)
void gemm_nt(const short* __restrict__ A, const short* __restrict__ B,
             float* __restrict__ outk, float* __restrict__ outv,
             short* __restrict__ qb, short* __restrict__ kb, short* __restrict__ vtb,
             float* __restrict__ outp, const float* __restrict__ bias) {
  const int K = EMB;
  __shared__ __align__(16) short As[2][128][64];
  __shared__ __align__(16) short Bs[2][128][64];
  int tid = threadIdx.x;
  int lane = tid & 63, wid = tid >> 6;
  int wm = wid >> 1, wn = wid & 1;
  int r16 = lane & 15, g4 = lane >> 4;
  int m0 = blockIdx.y * 128, n0 = blockIdx.x * 128;
  int lrow = lane >> 3, lcol = (lane & 7) * 8;
  f32x4 acc[4][4] = {};

#define STAGE(BUF, K0) do {                                          \
    _Pragma("unroll")                                                \
    for (int i = 0; i < 4; i++) {                                    \
      int r = wid * 32 + i * 8 + lrow;                               \
      gload16(A + (long)(m0 + r) * K + (K0) + lcol, &As[BUF][r][lcol]); \
      gload16(B + (long)(n0 + r) * K + (K0) + lcol, &Bs[BUF][r][lcol]); \
    } } while (0)

  STAGE(0, 0);
  int cur = 0;
  for (int t = 0; t < K / 64; t++) {
    __syncthreads();
    if (t + 1 < K / 64) STAGE(cur ^ 1, (t + 1) * 64);
#pragma unroll
    for (int s = 0; s < 2; s++) {
      short8 af[4], bf[4];
#pragma unroll
      for (int tt = 0; tt < 4; tt++) {
        af[tt] = *reinterpret_cast<const short8*>(&As[cur][wm * 64 + tt * 16 + r16][s * 32 + g4 * 8]);
        bf[tt] = *reinterpret_cast<const short8*>(&Bs[cur][wn * 64 + tt * 16 + r16][s * 32 + g4 * 8]);
      }
#pragma unroll
      for (int mt = 0; mt < 4; mt++)
#pragma unroll
        for (int nt = 0; nt < 4; nt++)
          acc[mt][nt] = __builtin_amdgcn_mfma_f32_16x16x32_bf16(af[mt], bf[nt], acc[mt][nt], 0, 0, 0);
    }
    cur ^= 1;
  }
#undef STAGE

#pragma unroll
  for (int mt = 0; mt < 4; mt++) {
    int nbase = m0 + wm * 64 + mt * 16 + g4 * 4;
#pragma unroll
    for (int nt = 0; nt < 4; nt++) {
      int f = n0 + wn * 64 + nt * 16 + r16;
#pragma unroll
      for (int r = 0; r < 4; r++) {
        float c = acc[mt][nt][r];
        int nn = nbase + r;
        if (MODE == 0) {
          int b = nn >> 11, s = nn & 2047;
          int sec = f / EMB; int fh = f - sec * EMB;
          int h = fh >> 6, d = fh & 63;
          int idx = (((b * NH) + h) * S_LEN + s) * HD + d;
          if (sec == 0) qb[idx] = f2bf(c);
          else if (sec == 1) { outk[idx] = c; kb[idx] = f2bf(c); }
          else { outv[idx] = c; vtb[(((b * NH) + h) * HD + d) * S_LEN + s] = f2bf(c); }
        } else {
          outp[(long)nn * EMB + f] = c + bias[f];
        }
      }
    }
  }
}

// Flash attention: uniform strip pairs + XCD affinity.
// K-only register ping-pong prefetch (+16 VGPR); V issued at body top and
// consumed after softmax (~450 cy later) -> latency hidden without state.
__global__ __launch_bounds__(256, 3)
void flash_attn6(const short* __restrict__ qb, const short* __restrict__ kb,
                 const short* __restrict__ vtb, short* __restrict__ mb) {
  const int tid = threadIdx.x;
  const int w = tid >> 6, lane = tid & 63;
  const int r16 = lane & 15, g4 = lane >> 4;
  const int id = blockIdx.x;
  const int xcd = id & 7, j = id >> 3;
  const int bh = xcd + 8 * (j >> 5);
  const int pair = j & 31;

  const short* qh = qb + (long)bh * S_LEN * HD;
  const short* kh = kb + (long)bh * S_LEN * HD;
  const short* vh = vtb + (long)bh * HD * S_LEN;

  __shared__ __align__(16) short P_lds[4][32][40];
  __shared__ __align__(16) float sca_lds[4][32];
  __shared__ float mlm[4][32], mll[4][32];
  __shared__ __align__(16) float wsc[4][32];
  __shared__ __align__(16) float o_lds[32][68];
  __shared__ float l_red[32];

#define ISSUEK(KP, KR0) do {                                         \
    const short* _kp = kh + ((KR0) + r16) * HD + g4 * 8;             \
    KP##0 = *reinterpret_cast<const short8*>(_kp);                   \
    KP##1 = *reinterpret_cast<const short8*>(_kp + 32);              \
    KP##2 = *reinterpret_cast<const short8*>(_kp + 16 * HD);         \
    KP##3 = *reinterpret_cast<const short8*>(_kp + 16 * HD + 32);    \
  } while (0)

// sNM: N = k-block, M = q-block. k-row = N*16+g4*4+r, q-col = M*16+r16.
#define BODY(KP, NK, KR0, DONEXT, KR0N) do {                                           \
    const int _k0 = (KR0);                                                             \
    const short* _vp = vh + r16 * S_LEN + _k0 + g4 * 8;                                \
    short8 v0 = *reinterpret_cast<const short8*>(_vp);                                 \
    short8 v1 = *reinterpret_cast<const short8*>(_vp + 16 * S_LEN);                    \
    short8 v2 = *reinterpret_cast<const short8*>(_vp + 32 * S_LEN);                    \
    short8 v3 = *reinterpret_cast<const short8*>(_vp + 48 * S_LEN);                    \
    f32x4 s00 = {0.f,0.f,0.f,0.f}, s01 = {0.f,0.f,0.f,0.f};                            \
    f32x4 s10 = {0.f,0.f,0.f,0.f}, s11 = {0.f,0.f,0.f,0.f};                            \
    s00 = __builtin_amdgcn_mfma_f32_16x16x32_bf16(KP##0, qf00, s00, 0, 0, 0);          \
    s00 = __builtin_amdgcn_mfma_f32_16x16x32_bf16(KP##1, qf01, s00, 0, 0, 0);          \
    s10 = __builtin_amdgcn_mfma_f32_16x16x32_bf16(KP##2, qf00, s10, 0, 0, 0);          \
    s10 = __builtin_amdgcn_mfma_f32_16x16x32_bf16(KP##3, qf01, s10, 0, 0, 0);          \
    s01 = __builtin_amdgcn_mfma_f32_16x16x32_bf16(KP##0, qf10, s01, 0, 0, 0);          \
    s01 = __builtin_amdgcn_mfma_f32_16x16x32_bf16(KP##1, qf11, s01, 0, 0, 0);          \
    s11 = __builtin_amdgcn_mfma_f32_16x16x32_bf16(KP##2, qf10, s11, 0, 0, 0);          \
    s11 = __builtin_amdgcn_mfma_f32_16x16x32_bf16(KP##3, qf11, s11, 0, 0, 0);          \
    if (DONEXT) { ISSUEK(NK, (KR0N)); }                                                \
    if (_k0 == diag_kr0) {                                                             \
      _Pragma("unroll")                                                                \
      for (int r = 0; r < 4; r++) {                                                    \
        if (g4 * 4 + r > r16)           s00[r] = -1e30f;                               \
        if (16 + g4 * 4 + r > r16)      s10[r] = -1e30f;                               \
        if (g4 * 4 + r > 16 + r16)      s01[r] = -1e30f;                               \
        if (16 + g4 * 4 + r > 16 + r16) s11[r] = -1e30f;                               \
      }                                                                                \
    }                                                                                  \
    float rm0, rm1;                                                                    \
    {                                                                                  \
      float a = fmaxf(fmaxf(s00[0], s00[1]), fmaxf(s00[2], s00[3]));                   \
      float b = fmaxf(fmaxf(s10[0], s10[1]), fmaxf(s10[2], s10[3]));                   \
      float x = fmaxf(a, b);                                                           \
      x = fmaxf(x, __shfl_xor(x, 16)); x = fmaxf(x, __shfl_xor(x, 32));                \
      rm0 = x;                                                                         \
      a = fmaxf(fmaxf(s01[0], s01[1]), fmaxf(s01[2], s01[3]));                         \
      b = fmaxf(fmaxf(s11[0], s11[1]), fmaxf(s11[2], s11[3]));                         \
      x = fmaxf(a, b);                                                                 \
      x = fmaxf(x, __shfl_xor(x, 16)); x = fmaxf(x, __shfl_xor(x, 32));                \
      rm1 = x;                                                                         \
    }                                                                                  \
    bool cond = (rm0 <= m0 + 8.f) && (rm1 <= m1 + 8.f);                                \
    if (!__all(cond)) {                                                                \
      float nm0 = fmaxf(m0, rm0), nm1 = fmaxf(m1, rm1);                                \
      float sca0 = __builtin_exp2f((m0 - nm0) * L2E);                                  \
      float sca1 = __builtin_exp2f((m1 - nm1) * L2E);                                  \
      m0 = nm0; m20 = nm0 * L2E; l0 *= sca0;                                           \
      m1 = nm1; m21 = nm1 * L2E; l1 *= sca1;                                           \
      if (g4 == 0) { sca_lds[w][r16] = sca0; sca_lds[w][16 + r16] = sca1; }            \
      f32x4 sr0 = *reinterpret_cast<const f32x4*>(&sca_lds[w][g4 * 4]);                \
      f32x4 sr1 = *reinterpret_cast<const f32x4*>(&sca_lds[w][16 + g4 * 4]);           \
      _Pragma("unroll")                                                                \
      for (int dt = 0; dt < 4; dt++)                                                   \
        _Pragma("unroll")                                                              \
        for (int r = 0; r < 4; r++) {                                                  \
          oacc[0][dt][r] *= sr0[r]; oacc[1][dt][r] *= sr1[r];                          \
        }                                                                              \
    }                                                                                  \
    float rs0 = 0.f, rs1 = 0.f;                                                        \
    _Pragma("unroll")                                                                  \
    for (int r = 0; r < 4; r++) {                                                      \
      s00[r] = __builtin_exp2f(fmaf(s00[r], L2E, -m20));                               \
      s10[r] = __builtin_exp2f(fmaf(s10[r], L2E, -m20));                               \
      s01[r] = __builtin_exp2f(fmaf(s01[r], L2E, -m21));                               \
      s11[r] = __builtin_exp2f(fmaf(s11[r], L2E, -m21));                               \
      rs0 += s00[r] + s10[r]; rs1 += s01[r] + s11[r];                                  \
    }                                                                                  \
    rs0 += __shfl_xor(rs0, 16); rs0 += __shfl_xor(rs0, 32);                            \
    rs1 += __shfl_xor(rs1, 16); rs1 += __shfl_xor(rs1, 32);                            \
    l0 += rs0; l1 += rs1;                                                              \
    {                                                                                  \
      uint2 wv;                                                                        \
      wv.x = pkbf(s00[0], s00[1]); wv.y = pkbf(s00[2], s00[3]);                        \
      *reinterpret_cast<uint2*>(&P_lds[w][r16][g4 * 4]) = wv;                          \
      wv.x = pkbf(s10[0], s10[1]); wv.y = pkbf(s10[2], s10[3]);                        \
      *reinterpret_cast<uint2*>(&P_lds[w][r16][16 + g4 * 4]) = wv;                     \
      wv.x = pkbf(s01[0], s01[1]); wv.y = pkbf(s01[2], s01[3]);                        \
      *reinterpret_cast<uint2*>(&P_lds[w][16 + r16][g4 * 4]) = wv;                     \
      wv.x = pkbf(s11[0], s11[1]); wv.y = pkbf(s11[2], s11[3]);                        \
      *reinterpret_cast<uint2*>(&P_lds[w][16 + r16][16 + g4 * 4]) = wv;                \
    }                                                                                  \
    short8 pa0 = *reinterpret_cast<const short8*>(&P_lds[w][r16][g4 * 8]);             \
    short8 pa1 = *reinterpret_cast<const short8*>(&P_lds[w][16 + r16][g4 * 8]);        \
    oacc[0][0] = __builtin_amdgcn_mfma_f32_16x16x32_bf16(pa0, v0, oacc[0][0], 0, 0, 0); \
    oacc[1][0] = __builtin_amdgcn_mfma_f32_16x16x32_bf16(pa1, v0, oacc[1][0], 0, 0, 0); \
    oacc[0][1] = __builtin_amdgcn_mfma_f32_16x16x32_bf16(pa0, v1, oacc[0][1], 0, 0, 0); \
    oacc[1][1] = __builtin_amdgcn_mfma_f32_16x16x32_bf16(pa1, v1, oacc[1][1], 0, 0, 0); \
    oacc[0][2] = __builtin_amdgcn_mfma_f32_16x16x32_bf16(pa0, v2, oacc[0][2], 0, 0, 0); \
    oacc[1][2] = __builtin_amdgcn_mfma_f32_16x16x32_bf16(pa1, v2, oacc[1][2], 0, 0, 0); \
    oacc[0][3] = __builtin_amdgcn_mfma_f32_16x16x32_bf16(pa0, v3, oacc[0][3], 0, 0, 0); \
    oacc[1][3] = __builtin_amdgcn_mfma_f32_16x16x32_bf16(pa1, v3, oacc[1][3], 0, 0, 0); \
  } while (0)

  for (int half = 0; half < 2; half++) {
    const int strip = half == 0 ? (63 - pair) : pair;
    const int q0 = strip * 32;
    const int nkt = strip + 1;
    const int diag_kr0 = (nkt - 1) * 32;

    __syncthreads();  // o_lds from previous half fully consumed
    for (int i = tid; i < 32 * 68; i += 256) (&o_lds[0][0])[i] = 0.f;

    short8 qf00 = *reinterpret_cast<const short8*>(qh + (q0 + r16) * HD + g4 * 8);
    short8 qf01 = *reinterpret_cast<const short8*>(qh + (q0 + r16) * HD + 32 + g4 * 8);
    short8 qf10 = *reinterpret_cast<const short8*>(qh + (q0 + 16 + r16) * HD + g4 * 8);
    short8 qf11 = *reinterpret_cast<const short8*>(qh + (q0 + 16 + r16) * HD + 32 + g4 * 8);

    float m0 = -1e30f, m1 = -1e30f;
    float m20 = -1.44e30f, m21 = -1.44e30f;
    float l0 = 0.f, l1 = 0.f;
    f32x4 oacc[2][4] = {};

    int base = nkt >> 2, rem = nkt & 3;
    int start = w * base + (w < rem ? w : rem);
    int count = base + (w < rem ? 1 : 0);

    short8 kA0, kA1, kA2, kA3, kB0, kB1, kB2, kB3;
    if (count > 0) ISSUEK(kA, start * 32);
    int it = 0;
    for (; it + 2 <= count; it += 2) {
      BODY(kA, kB, (start + it) * 32, true, (start + it + 1) * 32);
      BODY(kB, kA, (start + it + 1) * 32, it + 3 <= count, (start + it + 2) * 32);
    }
    if (it < count) BODY(kA, kB, (start + it) * 32, false, 0);

    // ---- block merge across the 4 KV-chunk waves ----
    if (g4 == 0) {
      mlm[w][r16] = m0; mll[w][r16] = l0;
      mlm[w][16 + r16] = m1; mll[w][16 + r16] = l1;
    }
    __syncthreads();
    if (tid < 32) {
      float M = fmaxf(fmaxf(mlm[0][tid], mlm[1][tid]), fmaxf(mlm[2][tid], mlm[3][tid]));
      float Ls = 0.f;
#pragma unroll
      for (int ww = 0; ww < 4; ww++) {
        float e = __builtin_exp2f((mlm[ww][tid] - M) * L2E);
        wsc[ww][tid] = e;
        Ls += e * mll[ww][tid];
      }
      l_red[tid] = Ls;
    }
    __syncthreads();
    {
      f32x4 fw0 = *reinterpret_cast<const f32x4*>(&wsc[w][g4 * 4]);
      f32x4 fw1 = *reinterpret_cast<const f32x4*>(&wsc[w][16 + g4 * 4]);
#pragma unroll
      for (int dt = 0; dt < 4; dt++)
#pragma unroll
        for (int r = 0; r < 4; r++) {
          atomicAdd(&o_lds[g4 * 4 + r][dt * 16 + r16], oacc[0][dt][r] * fw0[r]);
          atomicAdd(&o_lds[16 + g4 * 4 + r][dt * 16 + r16], oacc[1][dt][r] * fw1[r]);
        }
    }
    __syncthreads();
    {
      int q = tid >> 3, db = (tid & 7) * 8;
      float inv = 1.f / l_red[q];
      f32x4 a = *reinterpret_cast<const f32x4*>(&o_lds[q][db]);
      f32x4 b = *reinterpret_cast<const f32x4*>(&o_lds[q][db + 4]);
      short8 o8;
#pragma unroll
      for (int jj = 0; jj < 4; jj++) { o8[jj] = f2bf(a[jj] * inv); o8[4 + jj] = f2bf(b[jj] * inv); }
      int bb = bh / NH, h = bh % NH;
      *reinterpret_cast<short8*>(&mb[((long)(bb * S_LEN + q0 + q)) * EMB + h * HD + db]) = o8;
    }
  }
#undef BODY
#undef ISSUEK
}

extern "C" void kernel_launch(void* const* d_in, const int* in_sizes, int n_in,
                              void* d_out, int out_size, void* d_ws, size_t ws_size,
                              hipStream_t stream) {
  const float* x  = (const float*)d_in[0];
  const float* Wq = (const float*)d_in[1];
  const float* Wk = (const float*)d_in[2];
  const float* Wv = (const float*)d_in[3];
  const float* Wo = (const float*)d_in[4];
  const float* bo = (const float*)d_in[5];

  float* out  = (float*)d_out;
  float* outk = out + 3145728;
  float* outv = out + 6291456;

  short* ws  = (short*)d_ws;
  short* xb  = ws;                 // [4096][768]
  short* Wb  = xb + 3145728;       // [2304][768]  (Wq;Wk;Wv)
  short* Wob = Wb + 1769472;       // [768][768]
  short* qb  = Wob + 589824;       // [24][2048][64]
  short* kb  = qb + 3145728;       // [24][2048][64]
  short* vtb = kb + 3145728;       // [24][64][2048]  (V transposed per head)
  short* mb  = vtb + 3145728;      // [4096][768]    merged attn, bf16

  cvt_bf16<<<3072, 256, 0, stream>>>(x, xb, 3145728);
  cvt_w<<<dim3(576, 4), 256, 0, stream>>>(Wq, Wk, Wv, Wo, Wb, Wob);

  gemm_nt<0><<<dim3(18, 32), 256, 0, stream>>>(xb, Wb, outk, outv, qb, kb, vtb, nullptr, nullptr);
  flash_attn6<<<768, 256, 0, stream>>>(qb, kb, vtb, mb);
  gemm_nt<1><<<dim3(6, 32), 256, 0, stream>>>(mb, Wob, nullptr, nullptr, nullptr, nullptr, nullptr, out, bo);
}

// Round 8
// 162.258 us; speedup vs baseline: 1.3237x; 1.2057x over previous
//
#include <hip/hip_runtime.h>
#include <hip/hip_bf16.h>

#define S_LEN 2048
#define EMB 768
#define NH 12
#define HD 64
#define L2E 1.44269504088896340736f

typedef __attribute__((ext_vector_type(8))) short short8;
typedef __attribute__((ext_vector_type(4))) float f32x4;

typedef __attribute__((address_space(3))) void lds_t;
typedef __attribute__((address_space(1))) const void gbl_t;

__device__ __forceinline__ void gload16(const void* g, void* l) {
  __builtin_amdgcn_global_load_lds((gbl_t*)g, (lds_t*)l, 16, 0, 0);
}

__device__ __forceinline__ short f2bf(float f) {
  union { float f; unsigned u; } v; v.f = f;
  unsigned r = v.u + 0x7FFFu + ((v.u >> 16) & 1u);
  return (short)(r >> 16);
}

__device__ __forceinline__ unsigned pkbf(float a, float b) {
  unsigned r;
  asm("v_cvt_pk_bf16_f32 %0, %1, %2" : "=v"(r) : "v"(a), "v"(b));
  return r;
}

__global__ void cvt_bf16(const float* __restrict__ src, short* __restrict__ dst, int n) {
  int i = (blockIdx.x * blockDim.x + threadIdx.x) * 4;
  if (i >= n) return;
  float4 v = *reinterpret_cast<const float4*>(src + i);
  short4 o;
  o.x = f2bf(v.x); o.y = f2bf(v.y); o.z = f2bf(v.z); o.w = f2bf(v.w);
  *reinterpret_cast<short4*>(dst + i) = o;
}

__global__ void cvt_w(const float* __restrict__ Wq, const float* __restrict__ Wk,
                      const float* __restrict__ Wv, const float* __restrict__ Wo,
                      short* __restrict__ Wb, short* __restrict__ Wob) {
  int sec = blockIdx.y;
  const float* src = sec == 0 ? Wq : sec == 1 ? Wk : sec == 2 ? Wv : Wo;
  short* dst = sec < 3 ? Wb + sec * 589824 : Wob;
  int i = (blockIdx.x * blockDim.x + threadIdx.x) * 4;
  float4 v = *reinterpret_cast<const float4*>(src + i);
  short4 o;
  o.x = f2bf(v.x); o.y = f2bf(v.y); o.z = f2bf(v.z); o.w = f2bf(v.w);
  *reinterpret_cast<short4*>(dst + i) = o;
}

// NT GEMM, 2-phase double-buffered global_load_lds staging (R5/R6 proven).
template<int MODE>
__global__ __launch_bounds__(256)
void gemm_nt(const short* __restrict__ A, const short* __restrict__ B,
             float* __restrict__ outk, float* __restrict__ outv,
             short* __restrict__ qb, short* __restrict__ kb, short* __restrict__ vtb,
             float* __restrict__ outp, const float* __restrict__ bias) {
  const int K = EMB;
  __shared__ __align__(16) short As[2][128][64];
  __shared__ __align__(16) short Bs[2][128][64];
  int tid = threadIdx.x;
  int lane = tid & 63, wid = tid >> 6;
  int wm = wid >> 1, wn = wid & 1;
  int r16 = lane & 15, g4 = lane >> 4;
  int m0 = blockIdx.y * 128, n0 = blockIdx.x * 128;
  int lrow = lane >> 3, lcol = (lane & 7) * 8;
  f32x4 acc[4][4] = {};

#define STAGE(BUF, K0) do {                                          \
    _Pragma("unroll")                                                \
    for (int i = 0; i < 4; i++) {                                    \
      int r = wid * 32 + i * 8 + lrow;                               \
      gload16(A + (long)(m0 + r) * K + (K0) + lcol, &As[BUF][r][lcol]); \
      gload16(B + (long)(n0 + r) * K + (K0) + lcol, &Bs[BUF][r][lcol]); \
    } } while (0)

  STAGE(0, 0);
  int cur = 0;
  for (int t = 0; t < K / 64; t++) {
    __syncthreads();
    if (t + 1 < K / 64) STAGE(cur ^ 1, (t + 1) * 64);
#pragma unroll
    for (int s = 0; s < 2; s++) {
      short8 af[4], bf[4];
#pragma unroll
      for (int tt = 0; tt < 4; tt++) {
        af[tt] = *reinterpret_cast<const short8*>(&As[cur][wm * 64 + tt * 16 + r16][s * 32 + g4 * 8]);
        bf[tt] = *reinterpret_cast<const short8*>(&Bs[cur][wn * 64 + tt * 16 + r16][s * 32 + g4 * 8]);
      }
#pragma unroll
      for (int mt = 0; mt < 4; mt++)
#pragma unroll
        for (int nt = 0; nt < 4; nt++)
          acc[mt][nt] = __builtin_amdgcn_mfma_f32_16x16x32_bf16(af[mt], bf[nt], acc[mt][nt], 0, 0, 0);
    }
    cur ^= 1;
  }
#undef STAGE

#pragma unroll
  for (int mt = 0; mt < 4; mt++) {
    int nbase = m0 + wm * 64 + mt * 16 + g4 * 4;
#pragma unroll
    for (int nt = 0; nt < 4; nt++) {
      int f = n0 + wn * 64 + nt * 16 + r16;
#pragma unroll
      for (int r = 0; r < 4; r++) {
        float c = acc[mt][nt][r];
        int nn = nbase + r;
        if (MODE == 0) {
          int b = nn >> 11, s = nn & 2047;
          int sec = f / EMB; int fh = f - sec * EMB;
          int h = fh >> 6, d = fh & 63;
          int idx = (((b * NH) + h) * S_LEN + s) * HD + d;
          if (sec == 0) qb[idx] = f2bf(c);
          else if (sec == 1) { outk[idx] = c; kb[idx] = f2bf(c); }
          else { outv[idx] = c; vtb[(((b * NH) + h) * HD + d) * S_LEN + s] = f2bf(c); }
        } else {
          outp[(long)nn * EMB + f] = c + bias[f];
        }
      }
    }
  }
}

// Flash attention v8: shared-KV block structure.
// Block = 128-row Q-tile, 4 waves x 32 q-rows. K tile (32x64) async-staged
// into LDS (double-buffered, XOR-swizzled via pre-swizzled global source),
// shared by all 4 waves via ds_read_b128. V read from global (hidden under
// softmax; all waves read same addresses -> L1 hits). No split-KV merge.
// Grid 384 = 8 XCD-slots x 3 bh x 16 q-tiles, long q-tiles dispatched first.
__global__ __launch_bounds__(256)
void flash_attn8(const short* __restrict__ qb, const short* __restrict__ kb,
                 const short* __restrict__ vtb, short* __restrict__ mb) {
  const int tid = threadIdx.x;
  const int w = tid >> 6, lane = tid & 63;
  const int r16 = lane & 15, g4 = lane >> 4;
  const int id = blockIdx.x;
  const int xcd = id & 7, u = id >> 3;        // u in [0,48)
  const int bh = xcd + 8 * (u % 3);
  const int qt = 15 - u / 3;                  // long tiles first
  const int q0 = qt * 128;
  const int qw0 = q0 + w * 32;
  const int nkt = qt * 4 + 4;                 // block-level KV tiles (32 rows each)
  const int nkt_w = qt * 4 + w + 1;           // this wave's causal range
  const int diag_kt = nkt_w - 1;

  const short* qh = qb + (long)bh * S_LEN * HD;
  const short* kh = kb + (long)bh * S_LEN * HD;
  const short* vh = vtb + (long)bh * HD * S_LEN;

  __shared__ __align__(16) short Kl[2][32][64];
  __shared__ __align__(16) short P_lds[4][32][40];
  __shared__ __align__(16) float sca_lds[4][32];
  __shared__ __align__(16) float Olds[4][32][68];

  // K staging: thread covers row = w*8 + (lane>>3), 16B chunk = lane&7.
  // LDS dest linear (base + lane*16); global source column pre-swizzled by
  // chunk ^ (row&7) so the swizzled read below is conflict-free (rule #21).
  const int srow = lane >> 3, schunk = lane & 7;
  const short* ksrc = kh + (w * 8 + srow) * HD + ((schunk ^ srow) * 8);
  short* kdst0 = &Kl[0][w * 8 + srow][schunk * 8];
  short* kdst1 = &Kl[1][w * 8 + srow][schunk * 8];
#define KSTAGE(BUF, KR0) gload16(ksrc + (KR0) * HD, (BUF) ? kdst1 : kdst0)

  // Q fragments
  short8 qf00 = *reinterpret_cast<const short8*>(qh + (qw0 + r16) * HD + g4 * 8);
  short8 qf01 = *reinterpret_cast<const short8*>(qh + (qw0 + r16) * HD + 32 + g4 * 8);
  short8 qf10 = *reinterpret_cast<const short8*>(qh + (qw0 + 16 + r16) * HD + g4 * 8);
  short8 qf11 = *reinterpret_cast<const short8*>(qh + (qw0 + 16 + r16) * HD + 32 + g4 * 8);

  float m0 = -1e30f, m1 = -1e30f;
  float m20 = -1.44e30f, m21 = -1.44e30f;
  float l0 = 0.f, l1 = 0.f;
  f32x4 oacc[2][4] = {};

  const int kc0 = (g4 ^ (r16 & 7)) * 8;       // swizzled chunk offset (shorts)

  KSTAGE(0, 0);
  __syncthreads();  // buf0 resident

  for (int kt = 0; kt < nkt; kt++) {
    if (kt + 1 < nkt) KSTAGE((kt + 1) & 1, (kt + 1) * 32);

    if (kt < nkt_w) {
      const int kr0 = kt * 32;
      // V fragments (global; consumed after softmax -> latency hidden)
      const short* vp = vh + r16 * S_LEN + kr0 + g4 * 8;
      short8 v0 = *reinterpret_cast<const short8*>(vp);
      short8 v1 = *reinterpret_cast<const short8*>(vp + 16 * S_LEN);
      short8 v2 = *reinterpret_cast<const short8*>(vp + 32 * S_LEN);
      short8 v3 = *reinterpret_cast<const short8*>(vp + 48 * S_LEN);

      // K fragments from LDS (swizzled read; 2-way conflicts = free)
      const short* kbuf = &Kl[kt & 1][0][0];
      short8 k0 = *reinterpret_cast<const short8*>(kbuf + r16 * 64 + kc0);
      short8 k1 = *reinterpret_cast<const short8*>(kbuf + r16 * 64 + (kc0 ^ 32));
      short8 k2 = *reinterpret_cast<const short8*>(kbuf + (16 + r16) * 64 + kc0);
      short8 k3 = *reinterpret_cast<const short8*>(kbuf + (16 + r16) * 64 + (kc0 ^ 32));

      // S^T: sNM, N = k-block, M = q-block; k-row = N*16+g4*4+r, q-col = M*16+r16
      f32x4 s00 = {0.f, 0.f, 0.f, 0.f}, s01 = {0.f, 0.f, 0.f, 0.f};
      f32x4 s10 = {0.f, 0.f, 0.f, 0.f}, s11 = {0.f, 0.f, 0.f, 0.f};
      s00 = __builtin_amdgcn_mfma_f32_16x16x32_bf16(k0, qf00, s00, 0, 0, 0);
      s00 = __builtin_amdgcn_mfma_f32_16x16x32_bf16(k1, qf01, s00, 0, 0, 0);
      s10 = __builtin_amdgcn_mfma_f32_16x16x32_bf16(k2, qf00, s10, 0, 0, 0);
      s10 = __builtin_amdgcn_mfma_f32_16x16x32_bf16(k3, qf01, s10, 0, 0, 0);
      s01 = __builtin_amdgcn_mfma_f32_16x16x32_bf16(k0, qf10, s01, 0, 0, 0);
      s01 = __builtin_amdgcn_mfma_f32_16x16x32_bf16(k1, qf11, s01, 0, 0, 0);
      s11 = __builtin_amdgcn_mfma_f32_16x16x32_bf16(k2, qf10, s11, 0, 0, 0);
      s11 = __builtin_amdgcn_mfma_f32_16x16x32_bf16(k3, qf11, s11, 0, 0, 0);

      if (kt == diag_kt) {  // kr0 == qw0 here: relative mask valid
#pragma unroll
        for (int r = 0; r < 4; r++) {
          if (g4 * 4 + r > r16)           s00[r] = -1e30f;
          if (16 + g4 * 4 + r > r16)      s10[r] = -1e30f;
          if (g4 * 4 + r > 16 + r16)      s01[r] = -1e30f;
          if (16 + g4 * 4 + r > 16 + r16) s11[r] = -1e30f;
        }
      }

      float rm0, rm1;
      {
        float x = fmaxf(fmaxf(fmaxf(s00[0], s00[1]), fmaxf(s00[2], s00[3])),
                        fmaxf(fmaxf(s10[0], s10[1]), fmaxf(s10[2], s10[3])));
        x = fmaxf(x, __shfl_xor(x, 16)); x = fmaxf(x, __shfl_xor(x, 32));
        rm0 = x;
        x = fmaxf(fmaxf(fmaxf(s01[0], s01[1]), fmaxf(s01[2], s01[3])),
                  fmaxf(fmaxf(s11[0], s11[1]), fmaxf(s11[2], s11[3])));
        x = fmaxf(x, __shfl_xor(x, 16)); x = fmaxf(x, __shfl_xor(x, 32));
        rm1 = x;
      }

      bool cond = (rm0 <= m0 + 8.f) && (rm1 <= m1 + 8.f);
      if (!__all(cond)) {
        float nm0 = fmaxf(m0, rm0), nm1 = fmaxf(m1, rm1);
        float sca0 = __builtin_exp2f((m0 - nm0) * L2E);
        float sca1 = __builtin_exp2f((m1 - nm1) * L2E);
        m0 = nm0; m20 = nm0 * L2E; l0 *= sca0;
        m1 = nm1; m21 = nm1 * L2E; l1 *= sca1;
        if (g4 == 0) { sca_lds[w][r16] = sca0; sca_lds[w][16 + r16] = sca1; }
        f32x4 sr0 = *reinterpret_cast<const f32x4*>(&sca_lds[w][g4 * 4]);
        f32x4 sr1 = *reinterpret_cast<const f32x4*>(&sca_lds[w][16 + g4 * 4]);
#pragma unroll
        for (int dt = 0; dt < 4; dt++)
#pragma unroll
          for (int r = 0; r < 4; r++) {
            oacc[0][dt][r] *= sr0[r];
            oacc[1][dt][r] *= sr1[r];
          }
      }

      float rs0 = 0.f, rs1 = 0.f;
#pragma unroll
      for (int r = 0; r < 4; r++) {
        s00[r] = __builtin_exp2f(fmaf(s00[r], L2E, -m20));
        s10[r] = __builtin_exp2f(fmaf(s10[r], L2E, -m20));
        s01[r] = __builtin_exp2f(fmaf(s01[r], L2E, -m21));
        s11[r] = __builtin_exp2f(fmaf(s11[r], L2E, -m21));
        rs0 += s00[r] + s10[r];
        rs1 += s01[r] + s11[r];
      }
      rs0 += __shfl_xor(rs0, 16); rs0 += __shfl_xor(rs0, 32);
      rs1 += __shfl_xor(rs1, 16); rs1 += __shfl_xor(rs1, 32);
      l0 += rs0; l1 += rs1;

      {
        uint2 wv;
        wv.x = pkbf(s00[0], s00[1]); wv.y = pkbf(s00[2], s00[3]);
        *reinterpret_cast<uint2*>(&P_lds[w][r16][g4 * 4]) = wv;
        wv.x = pkbf(s10[0], s10[1]); wv.y = pkbf(s10[2], s10[3]);
        *reinterpret_cast<uint2*>(&P_lds[w][r16][16 + g4 * 4]) = wv;
        wv.x = pkbf(s01[0], s01[1]); wv.y = pkbf(s01[2], s01[3]);
        *reinterpret_cast<uint2*>(&P_lds[w][16 + r16][g4 * 4]) = wv;
        wv.x = pkbf(s11[0], s11[1]); wv.y = pkbf(s11[2], s11[3]);
        *reinterpret_cast<uint2*>(&P_lds[w][16 + r16][16 + g4 * 4]) = wv;
      }
      short8 pa0 = *reinterpret_cast<const short8*>(&P_lds[w][r16][g4 * 8]);
      short8 pa1 = *reinterpret_cast<const short8*>(&P_lds[w][16 + r16][g4 * 8]);

      oacc[0][0] = __builtin_amdgcn_mfma_f32_16x16x32_bf16(pa0, v0, oacc[0][0], 0, 0, 0);
      oacc[1][0] = __builtin_amdgcn_mfma_f32_16x16x32_bf16(pa1, v0, oacc[1][0], 0, 0, 0);
      oacc[0][1] = __builtin_amdgcn_mfma_f32_16x16x32_bf16(pa0, v1, oacc[0][1], 0, 0, 0);
      oacc[1][1] = __builtin_amdgcn_mfma_f32_16x16x32_bf16(pa1, v1, oacc[1][1], 0, 0, 0);
      oacc[0][2] = __builtin_amdgcn_mfma_f32_16x16x32_bf16(pa0, v2, oacc[0][2], 0, 0, 0);
      oacc[1][2] = __builtin_amdgcn_mfma_f32_16x16x32_bf16(pa1, v2, oacc[1][2], 0, 0, 0);
      oacc[0][3] = __builtin_amdgcn_mfma_f32_16x16x32_bf16(pa0, v3, oacc[0][3], 0, 0, 0);
      oacc[1][3] = __builtin_amdgcn_mfma_f32_16x16x32_bf16(pa1, v3, oacc[1][3], 0, 0, 0);
    }

    __syncthreads();  // drains KSTAGE (vmcnt) + syncs LDS readers
  }
#undef KSTAGE

  // ---- per-wave epilogue: divide by l, transpose via LDS, coalesced store ----
  if (g4 == 0) { sca_lds[w][r16] = l0; sca_lds[w][16 + r16] = l1; }
  f32x4 li0 = *reinterpret_cast<const f32x4*>(&sca_lds[w][g4 * 4]);
  f32x4 li1 = *reinterpret_cast<const f32x4*>(&sca_lds[w][16 + g4 * 4]);
  f32x4 iv0, iv1;
#pragma unroll
  for (int r = 0; r < 4; r++) { iv0[r] = 1.f / li0[r]; iv1[r] = 1.f / li1[r]; }
#pragma unroll
  for (int dt = 0; dt < 4; dt++)
#pragma unroll
    for (int r = 0; r < 4; r++) {
      Olds[w][g4 * 4 + r][dt * 16 + r16]      = oacc[0][dt][r] * iv0[r];
      Olds[w][16 + g4 * 4 + r][dt * 16 + r16] = oacc[1][dt][r] * iv1[r];
    }
  {
    int orow = lane >> 2, oc = (lane & 3) * 16;
    int bb = bh / NH, h = bh % NH;
#pragma unroll
    for (int half = 0; half < 2; half++) {
      int row = half * 16 + orow;
      f32x4 a0 = *reinterpret_cast<const f32x4*>(&Olds[w][row][oc]);
      f32x4 a1 = *reinterpret_cast<const f32x4*>(&Olds[w][row][oc + 4]);
      f32x4 a2 = *reinterpret_cast<const f32x4*>(&Olds[w][row][oc + 8]);
      f32x4 a3 = *reinterpret_cast<const f32x4*>(&Olds[w][row][oc + 12]);
      short8 sa, sb;
#pragma unroll
      for (int j = 0; j < 4; j++) {
        sa[j] = f2bf(a0[j]); sa[4 + j] = f2bf(a1[j]);
        sb[j] = f2bf(a2[j]); sb[4 + j] = f2bf(a3[j]);
      }
      short* dst = &mb[((long)(bb * S_LEN + qw0 + row)) * EMB + h * HD + oc];
      *reinterpret_cast<short8*>(dst) = sa;
      *reinterpret_cast<short8*>(dst + 8) = sb;
    }
  }
}

extern "C" void kernel_launch(void* const* d_in, const int* in_sizes, int n_in,
                              void* d_out, int out_size, void* d_ws, size_t ws_size,
                              hipStream_t stream) {
  const float* x  = (const float*)d_in[0];
  const float* Wq = (const float*)d_in[1];
  const float* Wk = (const float*)d_in[2];
  const float* Wv = (const float*)d_in[3];
  const float* Wo = (const float*)d_in[4];
  const float* bo = (const float*)d_in[5];

  float* out  = (float*)d_out;
  float* outk = out + 3145728;
  float* outv = out + 6291456;

  short* ws  = (short*)d_ws;
  short* xb  = ws;                 // [4096][768]
  short* Wb  = xb + 3145728;       // [2304][768]  (Wq;Wk;Wv)
  short* Wob = Wb + 1769472;       // [768][768]
  short* qb  = Wob + 589824;       // [24][2048][64]
  short* kb  = qb + 3145728;       // [24][2048][64]
  short* vtb = kb + 3145728;       // [24][64][2048]  (V transposed per head)
  short* mb  = vtb + 3145728;      // [4096][768]    merged attn, bf16

  cvt_bf16<<<3072, 256, 0, stream>>>(x, xb, 3145728);
  cvt_w<<<dim3(576, 4), 256, 0, stream>>>(Wq, Wk, Wv, Wo, Wb, Wob);

  gemm_nt<0><<<dim3(18, 32), 256, 0, stream>>>(xb, Wb, outk, outv, qb, kb, vtb, nullptr, nullptr);
  flash_attn8<<<384, 256, 0, stream>>>(qb, kb, vtb, mb);
  gemm_nt<1><<<dim3(6, 32), 256, 0, stream>>>(mb, Wob, nullptr, nullptr, nullptr, nullptr, nullptr, out, bo);
}

// Round 9
// 150.363 us; speedup vs baseline: 1.4284x; 1.0791x over previous
//
#include <hip/hip_runtime.h>
#include <hip/hip_bf16.h>

#define S_LEN 2048
#define EMB 768
#define NH 12
#define HD 64
#define L2E 1.44269504088896340736f

typedef __attribute__((ext_vector_type(8))) short short8;
typedef __attribute__((ext_vector_type(4))) float f32x4;

typedef __attribute__((address_space(3))) void lds_t;
typedef __attribute__((address_space(1))) const void gbl_t;

__device__ __forceinline__ void gload16(const void* g, void* l) {
  __builtin_amdgcn_global_load_lds((gbl_t*)g, (lds_t*)l, 16, 0, 0);
}

__device__ __forceinline__ short f2bf(float f) {
  union { float f; unsigned u; } v; v.f = f;
  unsigned r = v.u + 0x7FFFu + ((v.u >> 16) & 1u);
  return (short)(r >> 16);
}

__device__ __forceinline__ unsigned pkbf(float a, float b) {
  unsigned r;
  asm("v_cvt_pk_bf16_f32 %0, %1, %2" : "=v"(r) : "v"(a), "v"(b));
  return r;
}

__global__ void cvt_bf16(const float* __restrict__ src, short* __restrict__ dst, int n) {
  int i = (blockIdx.x * blockDim.x + threadIdx.x) * 4;
  if (i >= n) return;
  float4 v = *reinterpret_cast<const float4*>(src + i);
  short4 o;
  o.x = f2bf(v.x); o.y = f2bf(v.y); o.z = f2bf(v.z); o.w = f2bf(v.w);
  *reinterpret_cast<short4*>(dst + i) = o;
}

__global__ void cvt_w(const float* __restrict__ Wq, const float* __restrict__ Wk,
                      const float* __restrict__ Wv, const float* __restrict__ Wo,
                      short* __restrict__ Wb, short* __restrict__ Wob) {
  int sec = blockIdx.y;
  const float* src = sec == 0 ? Wq : sec == 1 ? Wk : sec == 2 ? Wv : Wo;
  short* dst = sec < 3 ? Wb + sec * 589824 : Wob;
  int i = (blockIdx.x * blockDim.x + threadIdx.x) * 4;
  float4 v = *reinterpret_cast<const float4*>(src + i);
  short4 o;
  o.x = f2bf(v.x); o.y = f2bf(v.y); o.z = f2bf(v.z); o.w = f2bf(v.w);
  *reinterpret_cast<short4*>(dst + i) = o;
}

// NT GEMM, 2-phase double-buffered global_load_lds staging (proven).
template<int MODE>
__global__ __launch_bounds__(256)
void gemm_nt(const short* __restrict__ A, const short* __restrict__ B,
             float* __restrict__ outk, float* __restrict__ outv,
             short* __restrict__ qb, short* __restrict__ kb, short* __restrict__ vtb,
             float* __restrict__ outp, const float* __restrict__ bias) {
  const int K = EMB;
  __shared__ __align__(16) short As[2][128][64];
  __shared__ __align__(16) short Bs[2][128][64];
  int tid = threadIdx.x;
  int lane = tid & 63, wid = tid >> 6;
  int wm = wid >> 1, wn = wid & 1;
  int r16 = lane & 15, g4 = lane >> 4;
  int m0 = blockIdx.y * 128, n0 = blockIdx.x * 128;
  int lrow = lane >> 3, lcol = (lane & 7) * 8;
  f32x4 acc[4][4] = {};

#define STAGE(BUF, K0) do {                                          \
    _Pragma("unroll")                                                \
    for (int i = 0; i < 4; i++) {                                    \
      int r = wid * 32 + i * 8 + lrow;                               \
      gload16(A + (long)(m0 + r) * K + (K0) + lcol, &As[BUF][r][lcol]); \
      gload16(B + (long)(n0 + r) * K + (K0) + lcol, &Bs[BUF][r][lcol]); \
    } } while (0)

  STAGE(0, 0);
  int cur = 0;
  for (int t = 0; t < K / 64; t++) {
    __syncthreads();
    if (t + 1 < K / 64) STAGE(cur ^ 1, (t + 1) * 64);
#pragma unroll
    for (int s = 0; s < 2; s++) {
      short8 af[4], bf[4];
#pragma unroll
      for (int tt = 0; tt < 4; tt++) {
        af[tt] = *reinterpret_cast<const short8*>(&As[cur][wm * 64 + tt * 16 + r16][s * 32 + g4 * 8]);
        bf[tt] = *reinterpret_cast<const short8*>(&Bs[cur][wn * 64 + tt * 16 + r16][s * 32 + g4 * 8]);
      }
#pragma unroll
      for (int mt = 0; mt < 4; mt++)
#pragma unroll
        for (int nt = 0; nt < 4; nt++)
          acc[mt][nt] = __builtin_amdgcn_mfma_f32_16x16x32_bf16(af[mt], bf[nt], acc[mt][nt], 0, 0, 0);
    }
    cur ^= 1;
  }
#undef STAGE

#pragma unroll
  for (int mt = 0; mt < 4; mt++) {
    int nbase = m0 + wm * 64 + mt * 16 + g4 * 4;
#pragma unroll
    for (int nt = 0; nt < 4; nt++) {
      int f = n0 + wn * 64 + nt * 16 + r16;
#pragma unroll
      for (int r = 0; r < 4; r++) {
        float c = acc[mt][nt][r];
        int nn = nbase + r;
        if (MODE == 0) {
          int b = nn >> 11, s = nn & 2047;
          int sec = f / EMB; int fh = f - sec * EMB;
          int h = fh >> 6, d = fh & 63;
          int idx = (((b * NH) + h) * S_LEN + s) * HD + d;
          if (sec == 0) qb[idx] = f2bf(c);
          else if (sec == 1) { outk[idx] = c; kb[idx] = f2bf(c); }
          else { outv[idx] = c; vtb[(((b * NH) + h) * HD + d) * S_LEN + s] = f2bf(c); }
        } else {
          outp[(long)nn * EMB + f] = c + bias[f];
        }
      }
    }
  }
}

// Flash attention v9: 64-row Q-tile, 4 waves x 16 q-rows, shared double-buffered
// K LDS staging (32x64, pre-swizzled source). Grid 768 = 8 XCD x 3 bh x 32
// q-tiles (longest first) -> ~3 blocks/CU co-resident for latency overlap.
__global__ __launch_bounds__(256)
void flash_attn9(const short* __restrict__ qb, const short* __restrict__ kb,
                 const short* __restrict__ vtb, short* __restrict__ mb) {
  const int tid = threadIdx.x;
  const int w = tid >> 6, lane = tid & 63;
  const int r16 = lane & 15, g4 = lane >> 4;
  const int id = blockIdx.x;
  const int xcd = id & 7, u = id >> 3;        // u in [0,96)
  const int bh = xcd + 8 * (u % 3);
  const int qt = 31 - u / 3;                  // longest tiles dispatched first
  const int qw0 = qt * 64 + w * 16;           // this wave's 16 q-rows
  const int nkt = 2 * qt + 2;                 // block KV-tile count (32 rows each)
  const int diag_kt = 2 * qt + (w >> 1);      // wave's diagonal tile
  const int nkt_w = diag_kt + 1;              // wave's causal range
  const int qoff = (w & 1) * 16;              // q offset within diagonal tile

  const short* qh = qb + (long)bh * S_LEN * HD;
  const short* kh = kb + (long)bh * S_LEN * HD;
  const short* vh = vtb + (long)bh * HD * S_LEN;

  __shared__ __align__(16) short Kl[2][32][64];
  __shared__ __align__(16) short P_lds[4][16][40];
  __shared__ __align__(16) float sca_lds[4][16];
  __shared__ __align__(16) float Olds[4][16][68];

  // K staging: 256 threads cover 32 rows x 8 chunks of 16B. LDS dest linear;
  // global source column pre-swizzled (chunk ^ (row&7)) -> swizzled read below
  // is conflict-free (rule #21).
  const int srow = tid >> 3, schunk = tid & 7;
  const short* ksrc = kh + srow * HD + ((schunk ^ (srow & 7)) * 8);
  short* kdst0 = &Kl[0][srow][schunk * 8];
  short* kdst1 = &Kl[1][srow][schunk * 8];
#define KSTAGE(BUF, KR0) gload16(ksrc + (KR0) * HD, (BUF) ? kdst1 : kdst0)

  short8 qf0 = *reinterpret_cast<const short8*>(qh + (qw0 + r16) * HD + g4 * 8);
  short8 qf1 = *reinterpret_cast<const short8*>(qh + (qw0 + r16) * HD + 32 + g4 * 8);

  float m0 = -1e30f, m20 = -1.44e30f, l0 = 0.f;
  f32x4 oacc[4] = {};

  const int kc0 = (g4 ^ (r16 & 7)) * 8;       // swizzled chunk offset (shorts)

  KSTAGE(0, 0);
  __syncthreads();  // buf0 resident

  for (int kt = 0; kt < nkt; kt++) {
    const bool active = kt < nkt_w;
    const int kr0 = kt * 32;
    short8 v0, v1, v2, v3;
    f32x4 s0 = {0.f, 0.f, 0.f, 0.f}, s1 = {0.f, 0.f, 0.f, 0.f};

    if (active) {
      // V fragments (global, L2-resident; consumed at PV -> latency hidden)
      const short* vp = vh + r16 * S_LEN + kr0 + g4 * 8;
      v0 = *reinterpret_cast<const short8*>(vp);
      v1 = *reinterpret_cast<const short8*>(vp + 16 * S_LEN);
      v2 = *reinterpret_cast<const short8*>(vp + 32 * S_LEN);
      v3 = *reinterpret_cast<const short8*>(vp + 48 * S_LEN);

      // K fragments from LDS (swizzled read)
      const short* kbuf = &Kl[kt & 1][0][0];
      short8 k0 = *reinterpret_cast<const short8*>(kbuf + r16 * 64 + kc0);
      short8 k1 = *reinterpret_cast<const short8*>(kbuf + r16 * 64 + (kc0 ^ 32));
      short8 k2 = *reinterpret_cast<const short8*>(kbuf + (16 + r16) * 64 + kc0);
      short8 k3 = *reinterpret_cast<const short8*>(kbuf + (16 + r16) * 64 + (kc0 ^ 32));

      // S^T: sN, N = k-block; k-row = N*16+g4*4+r, q-col = r16
      s0 = __builtin_amdgcn_mfma_f32_16x16x32_bf16(k0, qf0, s0, 0, 0, 0);
      s0 = __builtin_amdgcn_mfma_f32_16x16x32_bf16(k1, qf1, s0, 0, 0, 0);
      s1 = __builtin_amdgcn_mfma_f32_16x16x32_bf16(k2, qf0, s1, 0, 0, 0);
      s1 = __builtin_amdgcn_mfma_f32_16x16x32_bf16(k3, qf1, s1, 0, 0, 0);
    }

    // next K tile: issued after QK^T and after V loads -> PV waits vmcnt(1),
    // stage stays in flight until the end-of-iteration barrier.
    if (kt + 1 < nkt) KSTAGE((kt + 1) & 1, (kt + 1) * 32);

    if (active) {
      if (kt == diag_kt) {  // mask k > q within diagonal tile
#pragma unroll
        for (int r = 0; r < 4; r++) {
          if (g4 * 4 + r > qoff + r16)      s0[r] = -1e30f;
          if (16 + g4 * 4 + r > qoff + r16) s1[r] = -1e30f;
        }
      }

      float rm;
      {
        float x = fmaxf(fmaxf(fmaxf(s0[0], s0[1]), fmaxf(s0[2], s0[3])),
                        fmaxf(fmaxf(s1[0], s1[1]), fmaxf(s1[2], s1[3])));
        x = fmaxf(x, __shfl_xor(x, 16));
        x = fmaxf(x, __shfl_xor(x, 32));
        rm = x;
      }

      if (!__all(rm <= m0 + 8.f)) {
        float nm = fmaxf(m0, rm);
        float sca = __builtin_exp2f((m0 - nm) * L2E);
        m0 = nm; m20 = nm * L2E; l0 *= sca;
        if (g4 == 0) sca_lds[w][r16] = sca;
        f32x4 sr = *reinterpret_cast<const f32x4*>(&sca_lds[w][g4 * 4]);
#pragma unroll
        for (int dt = 0; dt < 4; dt++)
#pragma unroll
          for (int r = 0; r < 4; r++) oacc[dt][r] *= sr[r];
      }

      float rs = 0.f;
#pragma unroll
      for (int r = 0; r < 4; r++) {
        s0[r] = __builtin_exp2f(fmaf(s0[r], L2E, -m20));
        s1[r] = __builtin_exp2f(fmaf(s1[r], L2E, -m20));
        rs += s0[r] + s1[r];
      }
      rs += __shfl_xor(rs, 16);
      rs += __shfl_xor(rs, 32);
      l0 += rs;

      {
        uint2 wv;
        wv.x = pkbf(s0[0], s0[1]); wv.y = pkbf(s0[2], s0[3]);
        *reinterpret_cast<uint2*>(&P_lds[w][r16][g4 * 4]) = wv;
        wv.x = pkbf(s1[0], s1[1]); wv.y = pkbf(s1[2], s1[3]);
        *reinterpret_cast<uint2*>(&P_lds[w][r16][16 + g4 * 4]) = wv;
      }
      short8 pa = *reinterpret_cast<const short8*>(&P_lds[w][r16][g4 * 8]);

      oacc[0] = __builtin_amdgcn_mfma_f32_16x16x32_bf16(pa, v0, oacc[0], 0, 0, 0);
      oacc[1] = __builtin_amdgcn_mfma_f32_16x16x32_bf16(pa, v1, oacc[1], 0, 0, 0);
      oacc[2] = __builtin_amdgcn_mfma_f32_16x16x32_bf16(pa, v2, oacc[2], 0, 0, 0);
      oacc[3] = __builtin_amdgcn_mfma_f32_16x16x32_bf16(pa, v3, oacc[3], 0, 0, 0);
    }

    __syncthreads();  // drains KSTAGE (vmcnt) + protects both LDS buffers
  }
#undef KSTAGE

  // ---- per-wave epilogue: divide by l, transpose via LDS, coalesced store ----
  if (g4 == 0) sca_lds[w][r16] = l0;
  f32x4 li = *reinterpret_cast<const f32x4*>(&sca_lds[w][g4 * 4]);
  f32x4 iv;
#pragma unroll
  for (int r = 0; r < 4; r++) iv[r] = 1.f / li[r];
#pragma unroll
  for (int dt = 0; dt < 4; dt++)
#pragma unroll
    for (int r = 0; r < 4; r++)
      Olds[w][g4 * 4 + r][dt * 16 + r16] = oacc[dt][r] * iv[r];
  {
    int orow = lane >> 2, oc = (lane & 3) * 16;
    int bb = bh / NH, h = bh % NH;
    f32x4 a0 = *reinterpret_cast<const f32x4*>(&Olds[w][orow][oc]);
    f32x4 a1 = *reinterpret_cast<const f32x4*>(&Olds[w][orow][oc + 4]);
    f32x4 a2 = *reinterpret_cast<const f32x4*>(&Olds[w][orow][oc + 8]);
    f32x4 a3 = *reinterpret_cast<const f32x4*>(&Olds[w][orow][oc + 12]);
    short8 sa, sb;
#pragma unroll
    for (int j = 0; j < 4; j++) {
      sa[j] = f2bf(a0[j]); sa[4 + j] = f2bf(a1[j]);
      sb[j] = f2bf(a2[j]); sb[4 + j] = f2bf(a3[j]);
    }
    short* dst = &mb[((long)(bb * S_LEN + qw0 + orow)) * EMB + h * HD + oc];
    *reinterpret_cast<short8*>(dst) = sa;
    *reinterpret_cast<short8*>(dst + 8) = sb;
  }
}

extern "C" void kernel_launch(void* const* d_in, const int* in_sizes, int n_in,
                              void* d_out, int out_size, void* d_ws, size_t ws_size,
                              hipStream_t stream) {
  const float* x  = (const float*)d_in[0];
  const float* Wq = (const float*)d_in[1];
  const float* Wk = (const float*)d_in[2];
  const float* Wv = (const float*)d_in[3];
  const float* Wo = (const float*)d_in[4];
  const float* bo = (const float*)d_in[5];

  float* out  = (float*)d_out;
  float* outk = out + 3145728;
  float* outv = out + 6291456;

  short* ws  = (short*)d_ws;
  short* xb  = ws;                 // [4096][768]
  short* Wb  = xb + 3145728;       // [2304][768]  (Wq;Wk;Wv)
  short* Wob = Wb + 1769472;       // [768][768]
  short* qb  = Wob + 589824;       // [24][2048][64]
  short* kb  = qb + 3145728;       // [24][2048][64]
  short* vtb = kb + 3145728;       // [24][64][2048]  (V transposed per head)
  short* mb  = vtb + 3145728;      // [4096][768]    merged attn, bf16

  cvt_bf16<<<3072, 256, 0, stream>>>(x, xb, 3145728);
  cvt_w<<<dim3(576, 4), 256, 0, stream>>>(Wq, Wk, Wv, Wo, Wb, Wob);

  gemm_nt<0><<<dim3(18, 32), 256, 0, stream>>>(xb, Wb, outk, outv, qb, kb, vtb, nullptr, nullptr);
  flash_attn9<<<768, 256, 0, stream>>>(qb, kb, vtb, mb);
  gemm_nt<1><<<dim3(6, 32), 256, 0, stream>>>(mb, Wob, nullptr, nullptr, nullptr, nullptr, nullptr, out, bo);
}

// Round 10
// 144.618 us; speedup vs baseline: 1.4852x; 1.0397x over previous
//
#include <hip/hip_runtime.h>
#include <hip/hip_bf16.h>

#define S_LEN 2048
#define EMB 768
#define NH 12
#define HD 64
#define L2E 1.44269504088896340736f

typedef __attribute__((ext_vector_type(8))) short short8;
typedef __attribute__((ext_vector_type(4))) float f32x4;

typedef __attribute__((address_space(3))) void lds_t;
typedef __attribute__((address_space(1))) const void gbl_t;

__device__ __forceinline__ void gload16(const void* g, void* l) {
  __builtin_amdgcn_global_load_lds((gbl_t*)g, (lds_t*)l, 16, 0, 0);
}

__device__ __forceinline__ short f2bf(float f) {
  union { float f; unsigned u; } v; v.f = f;
  unsigned r = v.u + 0x7FFFu + ((v.u >> 16) & 1u);
  return (short)(r >> 16);
}

__device__ __forceinline__ unsigned pkbf(float a, float b) {
  unsigned r;
  asm("v_cvt_pk_bf16_f32 %0, %1, %2" : "=v"(r) : "v"(a), "v"(b));
  return r;
}

__global__ void cvt_bf16(const float* __restrict__ src, short* __restrict__ dst, int n) {
  int i = (blockIdx.x * blockDim.x + threadIdx.x) * 4;
  if (i >= n) return;
  float4 v = *reinterpret_cast<const float4*>(src + i);
  short4 o;
  o.x = f2bf(v.x); o.y = f2bf(v.y); o.z = f2bf(v.z); o.w = f2bf(v.w);
  *reinterpret_cast<short4*>(dst + i) = o;
}

__global__ void cvt_w(const float* __restrict__ Wq, const float* __restrict__ Wk,
                      const float* __restrict__ Wv, const float* __restrict__ Wo,
                      short* __restrict__ Wb, short* __restrict__ Wob) {
  int sec = blockIdx.y;
  const float* src = sec == 0 ? Wq : sec == 1 ? Wk : sec == 2 ? Wv : Wo;
  short* dst = sec < 3 ? Wb + sec * 589824 : Wob;
  int i = (blockIdx.x * blockDim.x + threadIdx.x) * 4;
  float4 v = *reinterpret_cast<const float4*>(src + i);
  short4 o;
  o.x = f2bf(v.x); o.y = f2bf(v.y); o.z = f2bf(v.z); o.w = f2bf(v.w);
  *reinterpret_cast<short4*>(dst + i) = o;
}

// NT GEMM, 2-phase double-buffered global_load_lds staging (proven).
template<int MODE>
__global__ __launch_bounds__(256)
void gemm_nt(const short* __restrict__ A, const short* __restrict__ B,
             float* __restrict__ outk, float* __restrict__ outv,
             short* __restrict__ qb, short* __restrict__ kb, short* __restrict__ vtb,
             float* __restrict__ outp, const float* __restrict__ bias) {
  const int K = EMB;
  __shared__ __align__(16) short As[2][128][64];
  __shared__ __align__(16) short Bs[2][128][64];
  int tid = threadIdx.x;
  int lane = tid & 63, wid = tid >> 6;
  int wm = wid >> 1, wn = wid & 1;
  int r16 = lane & 15, g4 = lane >> 4;
  int m0 = blockIdx.y * 128, n0 = blockIdx.x * 128;
  int lrow = lane >> 3, lcol = (lane & 7) * 8;
  f32x4 acc[4][4] = {};

#define STAGE(BUF, K0) do {                                          \
    _Pragma("unroll")                                                \
    for (int i = 0; i < 4; i++) {                                    \
      int r = wid * 32 + i * 8 + lrow;                               \
      gload16(A + (long)(m0 + r) * K + (K0) + lcol, &As[BUF][r][lcol]); \
      gload16(B + (long)(n0 + r) * K + (K0) + lcol, &Bs[BUF][r][lcol]); \
    } } while (0)

  STAGE(0, 0);
  int cur = 0;
  for (int t = 0; t < K / 64; t++) {
    __syncthreads();
    if (t + 1 < K / 64) STAGE(cur ^ 1, (t + 1) * 64);
#pragma unroll
    for (int s = 0; s < 2; s++) {
      short8 af[4], bf[4];
#pragma unroll
      for (int tt = 0; tt < 4; tt++) {
        af[tt] = *reinterpret_cast<const short8*>(&As[cur][wm * 64 + tt * 16 + r16][s * 32 + g4 * 8]);
        bf[tt] = *reinterpret_cast<const short8*>(&Bs[cur][wn * 64 + tt * 16 + r16][s * 32 + g4 * 8]);
      }
#pragma unroll
      for (int mt = 0; mt < 4; mt++)
#pragma unroll
        for (int nt = 0; nt < 4; nt++)
          acc[mt][nt] = __builtin_amdgcn_mfma_f32_16x16x32_bf16(af[mt], bf[nt], acc[mt][nt], 0, 0, 0);
    }
    cur ^= 1;
  }
#undef STAGE

#pragma unroll
  for (int mt = 0; mt < 4; mt++) {
    int nbase = m0 + wm * 64 + mt * 16 + g4 * 4;
#pragma unroll
    for (int nt = 0; nt < 4; nt++) {
      int f = n0 + wn * 64 + nt * 16 + r16;
#pragma unroll
      for (int r = 0; r < 4; r++) {
        float c = acc[mt][nt][r];
        int nn = nbase + r;
        if (MODE == 0) {
          int b = nn >> 11, s = nn & 2047;
          int sec = f / EMB; int fh = f - sec * EMB;
          int h = fh >> 6, d = fh & 63;
          int idx = (((b * NH) + h) * S_LEN + s) * HD + d;
          if (sec == 0) qb[idx] = f2bf(c);
          else if (sec == 1) { outk[idx] = c; kb[idx] = f2bf(c); }
          else { outv[idx] = c; vtb[(((b * NH) + h) * HD + d) * S_LEN + s] = f2bf(c); }
        } else {
          outp[(long)nn * EMB + f] = c + bias[f];
        }
      }
    }
  }
}

// Flash attention v10: 2-wave blocks (128 thr), one 32-row q-strip per block
// (wave = 16 rows), shared double-buffered K LDS staging (pre-swizzled src).
// Grid 1536 = 8 XCD x 3 bh x 64 strips, longest first -> 6 blocks/CU
// co-resident, LPT-balanced.
__global__ __launch_bounds__(128)
void flash_attn10(const short* __restrict__ qb, const short* __restrict__ kb,
                  const short* __restrict__ vtb, short* __restrict__ mb) {
  const int tid = threadIdx.x;
  const int w = tid >> 6, lane = tid & 63;
  const int r16 = lane & 15, g4 = lane >> 4;
  const int id = blockIdx.x;
  const int xcd = id & 7, u = id >> 3;        // u in [0,192)
  const int bh = xcd + 8 * (u % 3);
  const int strip = 63 - u / 3;               // longest strips dispatched first
  const int qw0 = strip * 32 + w * 16;        // this wave's 16 q-rows
  const int nkt = strip + 1;                  // KV tiles (32 rows each)
  const int diag_kt = strip;
  const int qoff = w * 16;                    // q offset within diagonal tile

  const short* qh = qb + (long)bh * S_LEN * HD;
  const short* kh = kb + (long)bh * S_LEN * HD;
  const short* vh = vtb + (long)bh * HD * S_LEN;

  __shared__ __align__(16) short Kl[2][32][64];
  __shared__ __align__(16) short P_lds[2][16][40];
  __shared__ __align__(16) float sca_lds[2][16];
  __shared__ __align__(16) float Olds[2][16][68];

  // K staging: 128 threads cover 32 rows x 8 chunks of 16B (2 chunks/thread).
  // LDS dest linear; global source column pre-swizzled (chunk ^ (row&7)) so
  // the swizzled read below is conflict-free (rule #21).
  const int srow = tid >> 3, schunk = tid & 7;  // srow 0..15 -> rows srow, srow+16
  const short* ksrc = kh + srow * HD + ((schunk ^ (srow & 7)) * 8);
  short* kdstA0 = &Kl[0][srow][schunk * 8];
  short* kdstA1 = &Kl[0][srow + 16][schunk * 8];
  short* kdstB0 = &Kl[1][srow][schunk * 8];
  short* kdstB1 = &Kl[1][srow + 16][schunk * 8];
#define KSTAGE(BUF, KR0) do {                                   \
    gload16(ksrc + (KR0) * HD, (BUF) ? kdstB0 : kdstA0);        \
    gload16(ksrc + ((KR0) + 16) * HD, (BUF) ? kdstB1 : kdstA1); \
  } while (0)

  short8 qf0 = *reinterpret_cast<const short8*>(qh + (qw0 + r16) * HD + g4 * 8);
  short8 qf1 = *reinterpret_cast<const short8*>(qh + (qw0 + r16) * HD + 32 + g4 * 8);

  float m0 = -1e30f, m20 = -1.44e30f, l0 = 0.f;
  f32x4 oacc[4] = {};

  const int kc0 = (g4 ^ (r16 & 7)) * 8;       // swizzled chunk offset (shorts)

  KSTAGE(0, 0);
  __syncthreads();  // buf0 resident

  for (int kt = 0; kt < nkt; kt++) {
    const int kr0 = kt * 32;

    // V fragments (global, L2-resident; consumed at PV -> latency hidden)
    const short* vp = vh + r16 * S_LEN + kr0 + g4 * 8;
    short8 v0 = *reinterpret_cast<const short8*>(vp);
    short8 v1 = *reinterpret_cast<const short8*>(vp + 16 * S_LEN);
    short8 v2 = *reinterpret_cast<const short8*>(vp + 32 * S_LEN);
    short8 v3 = *reinterpret_cast<const short8*>(vp + 48 * S_LEN);

    // K fragments from LDS (swizzled read)
    const short* kbuf = &Kl[kt & 1][0][0];
    short8 k0 = *reinterpret_cast<const short8*>(kbuf + r16 * 64 + kc0);
    short8 k1 = *reinterpret_cast<const short8*>(kbuf + r16 * 64 + (kc0 ^ 32));
    short8 k2 = *reinterpret_cast<const short8*>(kbuf + (16 + r16) * 64 + kc0);
    short8 k3 = *reinterpret_cast<const short8*>(kbuf + (16 + r16) * 64 + (kc0 ^ 32));

    // S^T: sN, N = k-block; k-row = N*16+g4*4+r, q-col = r16
    f32x4 s0 = {0.f, 0.f, 0.f, 0.f}, s1 = {0.f, 0.f, 0.f, 0.f};
    s0 = __builtin_amdgcn_mfma_f32_16x16x32_bf16(k0, qf0, s0, 0, 0, 0);
    s0 = __builtin_amdgcn_mfma_f32_16x16x32_bf16(k1, qf1, s0, 0, 0, 0);
    s1 = __builtin_amdgcn_mfma_f32_16x16x32_bf16(k2, qf0, s1, 0, 0, 0);
    s1 = __builtin_amdgcn_mfma_f32_16x16x32_bf16(k3, qf1, s1, 0, 0, 0);

    // next K tile: issued after QK^T and V loads -> stays in flight to barrier
    if (kt + 1 < nkt) KSTAGE((kt + 1) & 1, (kt + 1) * 32);

    if (kt == diag_kt) {  // mask k > q within diagonal tile
#pragma unroll
      for (int r = 0; r < 4; r++) {
        if (g4 * 4 + r > qoff + r16)      s0[r] = -1e30f;
        if (16 + g4 * 4 + r > qoff + r16) s1[r] = -1e30f;
      }
    }

    float rm;
    {
      float x = fmaxf(fmaxf(fmaxf(s0[0], s0[1]), fmaxf(s0[2], s0[3])),
                      fmaxf(fmaxf(s1[0], s1[1]), fmaxf(s1[2], s1[3])));
      x = fmaxf(x, __shfl_xor(x, 16));
      x = fmaxf(x, __shfl_xor(x, 32));
      rm = x;
    }

    if (!__all(rm <= m0 + 8.f)) {
      float nm = fmaxf(m0, rm);
      float sca = __builtin_exp2f((m0 - nm) * L2E);
      m0 = nm; m20 = nm * L2E; l0 *= sca;
      if (g4 == 0) sca_lds[w][r16] = sca;
      f32x4 sr = *reinterpret_cast<const f32x4*>(&sca_lds[w][g4 * 4]);
#pragma unroll
      for (int dt = 0; dt < 4; dt++)
#pragma unroll
        for (int r = 0; r < 4; r++) oacc[dt][r] *= sr[r];
    }

    float rs = 0.f;
#pragma unroll
    for (int r = 0; r < 4; r++) {
      s0[r] = __builtin_exp2f(fmaf(s0[r], L2E, -m20));
      s1[r] = __builtin_exp2f(fmaf(s1[r], L2E, -m20));
      rs += s0[r] + s1[r];
    }
    rs += __shfl_xor(rs, 16);
    rs += __shfl_xor(rs, 32);
    l0 += rs;

    {
      uint2 wv;
      wv.x = pkbf(s0[0], s0[1]); wv.y = pkbf(s0[2], s0[3]);
      *reinterpret_cast<uint2*>(&P_lds[w][r16][g4 * 4]) = wv;
      wv.x = pkbf(s1[0], s1[1]); wv.y = pkbf(s1[2], s1[3]);
      *reinterpret_cast<uint2*>(&P_lds[w][r16][16 + g4 * 4]) = wv;
    }
    short8 pa = *reinterpret_cast<const short8*>(&P_lds[w][r16][g4 * 8]);

    oacc[0] = __builtin_amdgcn_mfma_f32_16x16x32_bf16(pa, v0, oacc[0], 0, 0, 0);
    oacc[1] = __builtin_amdgcn_mfma_f32_16x16x32_bf16(pa, v1, oacc[1], 0, 0, 0);
    oacc[2] = __builtin_amdgcn_mfma_f32_16x16x32_bf16(pa, v2, oacc[2], 0, 0, 0);
    oacc[3] = __builtin_amdgcn_mfma_f32_16x16x32_bf16(pa, v3, oacc[3], 0, 0, 0);

    __syncthreads();  // drains KSTAGE (vmcnt) + protects both LDS buffers
  }
#undef KSTAGE

  // ---- per-wave epilogue: divide by l, transpose via LDS, coalesced store ----
  if (g4 == 0) sca_lds[w][r16] = l0;
  f32x4 li = *reinterpret_cast<const f32x4*>(&sca_lds[w][g4 * 4]);
  f32x4 iv;
#pragma unroll
  for (int r = 0; r < 4; r++) iv[r] = 1.f / li[r];
#pragma unroll
  for (int dt = 0; dt < 4; dt++)
#pragma unroll
    for (int r = 0; r < 4; r++)
      Olds[w][g4 * 4 + r][dt * 16 + r16] = oacc[dt][r] * iv[r];
  {
    int orow = lane >> 2, oc = (lane & 3) * 16;
    int bb = bh / NH, h = bh % NH;
    f32x4 a0 = *reinterpret_cast<const f32x4*>(&Olds[w][orow][oc]);
    f32x4 a1 = *reinterpret_cast<const f32x4*>(&Olds[w][orow][oc + 4]);
    f32x4 a2 = *reinterpret_cast<const f32x4*>(&Olds[w][orow][oc + 8]);
    f32x4 a3 = *reinterpret_cast<const f32x4*>(&Olds[w][orow][oc + 12]);
    short8 sa, sb;
#pragma unroll
    for (int j = 0; j < 4; j++) {
      sa[j] = f2bf(a0[j]); sa[4 + j] = f2bf(a1[j]);
      sb[j] = f2bf(a2[j]); sb[4 + j] = f2bf(a3[j]);
    }
    short* dst = &mb[((long)(bb * S_LEN + qw0 + orow)) * EMB + h * HD + oc];
    *reinterpret_cast<short8*>(dst) = sa;
    *reinterpret_cast<short8*>(dst + 8) = sb;
  }
}

extern "C" void kernel_launch(void* const* d_in, const int* in_sizes, int n_in,
                              void* d_out, int out_size, void* d_ws, size_t ws_size,
                              hipStream_t stream) {
  const float* x  = (const float*)d_in[0];
  const float* Wq = (const float*)d_in[1];
  const float* Wk = (const float*)d_in[2];
  const float* Wv = (const float*)d_in[3];
  const float* Wo = (const float*)d_in[4];
  const float* bo = (const float*)d_in[5];

  float* out  = (float*)d_out;
  float* outk = out + 3145728;
  float* outv = out + 6291456;

  short* ws  = (short*)d_ws;
  short* xb  = ws;                 // [4096][768]
  short* Wb  = xb + 3145728;       // [2304][768]  (Wq;Wk;Wv)
  short* Wob = Wb + 1769472;       // [768][768]
  short* qb  = Wob + 589824;       // [24][2048][64]
  short* kb  = qb + 3145728;       // [24][2048][64]
  short* vtb = kb + 3145728;       // [24][64][2048]  (V transposed per head)
  short* mb  = vtb + 3145728;      // [4096][768]    merged attn, bf16

  cvt_bf16<<<3072, 256, 0, stream>>>(x, xb, 3145728);
  cvt_w<<<dim3(576, 4), 256, 0, stream>>>(Wq, Wk, Wv, Wo, Wb, Wob);

  gemm_nt<0><<<dim3(18, 32), 256, 0, stream>>>(xb, Wb, outk, outv, qb, kb, vtb, nullptr, nullptr);
  flash_attn10<<<1536, 128, 0, stream>>>(qb, kb, vtb, mb);
  gemm_nt<1><<<dim3(6, 32), 256, 0, stream>>>(mb, Wob, nullptr, nullptr, nullptr, nullptr, nullptr, out, bo);
}

// Round 11
// 144.266 us; speedup vs baseline: 1.4888x; 1.0024x over previous
//
#include <hip/hip_runtime.h>
#include <hip/hip_bf16.h>

#define S_LEN 2048
#define EMB 768
#define NH 12
#define HD 64
#define L2E 1.44269504088896340736f

typedef __attribute__((ext_vector_type(8))) short short8;
typedef __attribute__((ext_vector_type(4))) float f32x4;

typedef __attribute__((address_space(3))) void lds_t;
typedef __attribute__((address_space(1))) const void gbl_t;

__device__ __forceinline__ void gload16(const void* g, void* l) {
  __builtin_amdgcn_global_load_lds((gbl_t*)g, (lds_t*)l, 16, 0, 0);
}

__device__ __forceinline__ short f2bf(float f) {
  union { float f; unsigned u; } v; v.f = f;
  unsigned r = v.u + 0x7FFFu + ((v.u >> 16) & 1u);
  return (short)(r >> 16);
}

__device__ __forceinline__ unsigned pkbf(float a, float b) {
  unsigned r;
  asm("v_cvt_pk_bf16_f32 %0, %1, %2" : "=v"(r) : "v"(a), "v"(b));
  return r;
}

__global__ void cvt_bf16(const float* __restrict__ src, short* __restrict__ dst, int n) {
  int i = (blockIdx.x * blockDim.x + threadIdx.x) * 4;
  if (i >= n) return;
  float4 v = *reinterpret_cast<const float4*>(src + i);
  short4 o;
  o.x = f2bf(v.x); o.y = f2bf(v.y); o.z = f2bf(v.z); o.w = f2bf(v.w);
  *reinterpret_cast<short4*>(dst + i) = o;
}

__global__ void cvt_w(const float* __restrict__ Wq, const float* __restrict__ Wk,
                      const float* __restrict__ Wv, const float* __restrict__ Wo,
                      short* __restrict__ Wb, short* __restrict__ Wob) {
  int sec = blockIdx.y;
  const float* src = sec == 0 ? Wq : sec == 1 ? Wk : sec == 2 ? Wv : Wo;
  short* dst = sec < 3 ? Wb + sec * 589824 : Wob;
  int i = (blockIdx.x * blockDim.x + threadIdx.x) * 4;
  float4 v = *reinterpret_cast<const float4*>(src + i);
  short4 o;
  o.x = f2bf(v.x); o.y = f2bf(v.y); o.z = f2bf(v.z); o.w = f2bf(v.w);
  *reinterpret_cast<short4*>(dst + i) = o;
}

// NT GEMM, 2-phase double-buffered global_load_lds staging (proven).
template<int MODE>
__global__ __launch_bounds__(256)
void gemm_nt(const short* __restrict__ A, const short* __restrict__ B,
             float* __restrict__ outk, float* __restrict__ outv,
             short* __restrict__ qb, short* __restrict__ kb, short* __restrict__ vtb,
             float* __restrict__ outp, const float* __restrict__ bias) {
  const int K = EMB;
  __shared__ __align__(16) short As[2][128][64];
  __shared__ __align__(16) short Bs[2][128][64];
  int tid = threadIdx.x;
  int lane = tid & 63, wid = tid >> 6;
  int wm = wid >> 1, wn = wid & 1;
  int r16 = lane & 15, g4 = lane >> 4;
  int m0 = blockIdx.y * 128, n0 = blockIdx.x * 128;
  int lrow = lane >> 3, lcol = (lane & 7) * 8;
  f32x4 acc[4][4] = {};

#define STAGE(BUF, K0) do {                                          \
    _Pragma("unroll")                                                \
    for (int i = 0; i < 4; i++) {                                    \
      int r = wid * 32 + i * 8 + lrow;                               \
      gload16(A + (long)(m0 + r) * K + (K0) + lcol, &As[BUF][r][lcol]); \
      gload16(B + (long)(n0 + r) * K + (K0) + lcol, &Bs[BUF][r][lcol]); \
    } } while (0)

  STAGE(0, 0);
  int cur = 0;
  for (int t = 0; t < K / 64; t++) {
    __syncthreads();
    if (t + 1 < K / 64) STAGE(cur ^ 1, (t + 1) * 64);
#pragma unroll
    for (int s = 0; s < 2; s++) {
      short8 af[4], bf[4];
#pragma unroll
      for (int tt = 0; tt < 4; tt++) {
        af[tt] = *reinterpret_cast<const short8*>(&As[cur][wm * 64 + tt * 16 + r16][s * 32 + g4 * 8]);
        bf[tt] = *reinterpret_cast<const short8*>(&Bs[cur][wn * 64 + tt * 16 + r16][s * 32 + g4 * 8]);
      }
#pragma unroll
      for (int mt = 0; mt < 4; mt++)
#pragma unroll
        for (int nt = 0; nt < 4; nt++)
          acc[mt][nt] = __builtin_amdgcn_mfma_f32_16x16x32_bf16(af[mt], bf[nt], acc[mt][nt], 0, 0, 0);
    }
    cur ^= 1;
  }
#undef STAGE

#pragma unroll
  for (int mt = 0; mt < 4; mt++) {
    int nbase = m0 + wm * 64 + mt * 16 + g4 * 4;
#pragma unroll
    for (int nt = 0; nt < 4; nt++) {
      int f = n0 + wn * 64 + nt * 16 + r16;
#pragma unroll
      for (int r = 0; r < 4; r++) {
        float c = acc[mt][nt][r];
        int nn = nbase + r;
        if (MODE == 0) {
          int b = nn >> 11, s = nn & 2047;
          int sec = f / EMB; int fh = f - sec * EMB;
          int h = fh >> 6, d = fh & 63;
          int idx = (((b * NH) + h) * S_LEN + s) * HD + d;
          if (sec == 0) qb[idx] = f2bf(c);
          else if (sec == 1) { outk[idx] = c; kb[idx] = f2bf(c); }
          else { outv[idx] = c; vtb[(((b * NH) + h) * HD + d) * S_LEN + s] = f2bf(c); }
        } else {
          outp[(long)nn * EMB + f] = c + bias[f];
        }
      }
    }
  }
}

// Flash attention v11: v10 structure + shuffle-free common-case softmax.
// - l kept as per-lane partial, reduced once in epilogue (removes 2 shfl/iter)
// - per-lane rm_local + __all defer-max guard: cross-lane max/rescale only on
//   the rare max-growth path (removes 2 more shfl/iter in steady state)
__global__ __launch_bounds__(128)
void flash_attn11(const short* __restrict__ qb, const short* __restrict__ kb,
                  const short* __restrict__ vtb, short* __restrict__ mb) {
  const int tid = threadIdx.x;
  const int w = tid >> 6, lane = tid & 63;
  const int r16 = lane & 15, g4 = lane >> 4;
  const int id = blockIdx.x;
  const int xcd = id & 7, u = id >> 3;        // u in [0,192)
  const int bh = xcd + 8 * (u % 3);
  const int strip = 63 - u / 3;               // longest strips dispatched first
  const int qw0 = strip * 32 + w * 16;        // this wave's 16 q-rows
  const int nkt = strip + 1;                  // KV tiles (32 rows each)
  const int diag_kt = strip;
  const int qoff = w * 16;                    // q offset within diagonal tile

  const short* qh = qb + (long)bh * S_LEN * HD;
  const short* kh = kb + (long)bh * S_LEN * HD;
  const short* vh = vtb + (long)bh * HD * S_LEN;

  __shared__ __align__(16) short Kl[2][32][64];
  __shared__ __align__(16) short P_lds[2][16][40];
  __shared__ __align__(16) float sca_lds[2][16];
  __shared__ __align__(16) float Olds[2][16][68];

  // K staging: 128 threads cover 32 rows x 8 chunks of 16B (2 chunks/thread).
  // LDS dest linear; source column pre-swizzled (chunk ^ (row&7)) (rule #21).
  const int srow = tid >> 3, schunk = tid & 7;
  const short* ksrc = kh + srow * HD + ((schunk ^ (srow & 7)) * 8);
  short* kdstA0 = &Kl[0][srow][schunk * 8];
  short* kdstA1 = &Kl[0][srow + 16][schunk * 8];
  short* kdstB0 = &Kl[1][srow][schunk * 8];
  short* kdstB1 = &Kl[1][srow + 16][schunk * 8];
#define KSTAGE(BUF, KR0) do {                                   \
    gload16(ksrc + (KR0) * HD, (BUF) ? kdstB0 : kdstA0);        \
    gload16(ksrc + ((KR0) + 16) * HD, (BUF) ? kdstB1 : kdstA1); \
  } while (0)

  short8 qf0 = *reinterpret_cast<const short8*>(qh + (qw0 + r16) * HD + g4 * 8);
  short8 qf1 = *reinterpret_cast<const short8*>(qh + (qw0 + r16) * HD + 32 + g4 * 8);

  float m0 = -1e30f, m20 = -1.44e30f;
  float l0 = 0.f;                             // PER-LANE partial row sum
  f32x4 oacc[4] = {};

  const int kc0 = (g4 ^ (r16 & 7)) * 8;       // swizzled chunk offset (shorts)

  KSTAGE(0, 0);
  __syncthreads();  // buf0 resident

  for (int kt = 0; kt < nkt; kt++) {
    const int kr0 = kt * 32;

    // V fragments (global, L2-resident; consumed at PV -> latency hidden)
    const short* vp = vh + r16 * S_LEN + kr0 + g4 * 8;
    short8 v0 = *reinterpret_cast<const short8*>(vp);
    short8 v1 = *reinterpret_cast<const short8*>(vp + 16 * S_LEN);
    short8 v2 = *reinterpret_cast<const short8*>(vp + 32 * S_LEN);
    short8 v3 = *reinterpret_cast<const short8*>(vp + 48 * S_LEN);

    // K fragments from LDS (swizzled read)
    const short* kbuf = &Kl[kt & 1][0][0];
    short8 k0 = *reinterpret_cast<const short8*>(kbuf + r16 * 64 + kc0);
    short8 k1 = *reinterpret_cast<const short8*>(kbuf + r16 * 64 + (kc0 ^ 32));
    short8 k2 = *reinterpret_cast<const short8*>(kbuf + (16 + r16) * 64 + kc0);
    short8 k3 = *reinterpret_cast<const short8*>(kbuf + (16 + r16) * 64 + (kc0 ^ 32));

    // S^T: sN, N = k-block; k-row = N*16+g4*4+r, q-col = r16
    f32x4 s0 = {0.f, 0.f, 0.f, 0.f}, s1 = {0.f, 0.f, 0.f, 0.f};
    s0 = __builtin_amdgcn_mfma_f32_16x16x32_bf16(k0, qf0, s0, 0, 0, 0);
    s0 = __builtin_amdgcn_mfma_f32_16x16x32_bf16(k1, qf1, s0, 0, 0, 0);
    s1 = __builtin_amdgcn_mfma_f32_16x16x32_bf16(k2, qf0, s1, 0, 0, 0);
    s1 = __builtin_amdgcn_mfma_f32_16x16x32_bf16(k3, qf1, s1, 0, 0, 0);

    // next K tile: issued after QK^T and V loads -> stays in flight to barrier
    if (kt + 1 < nkt) KSTAGE((kt + 1) & 1, (kt + 1) * 32);

    if (kt == diag_kt) {  // mask k > q within diagonal tile
#pragma unroll
      for (int r = 0; r < 4; r++) {
        if (g4 * 4 + r > qoff + r16)      s0[r] = -1e30f;
        if (16 + g4 * 4 + r > qoff + r16) s1[r] = -1e30f;
      }
    }

    // per-lane max over this lane's 8 k-values (register axis only)
    float rm_local = fmaxf(fmaxf(fmaxf(s0[0], s0[1]), fmaxf(s0[2], s0[3])),
                           fmaxf(fmaxf(s1[0], s1[1]), fmaxf(s1[2], s1[3])));

    // defer-max: only when ANY lane's local max exceeds m0+8 do the exact
    // cross-lane max + rescale. m0 only updates via the fully-reduced path,
    // so all 4 lanes of a q stay consistent.
    if (!__all(rm_local <= m0 + 8.f)) {
      float x = rm_local;
      x = fmaxf(x, __shfl_xor(x, 16));
      x = fmaxf(x, __shfl_xor(x, 32));
      float nm = fmaxf(m0, x);
      float sca = __builtin_exp2f((m0 - nm) * L2E);
      m0 = nm; m20 = nm * L2E; l0 *= sca;
      if (g4 == 0) sca_lds[w][r16] = sca;
      f32x4 sr = *reinterpret_cast<const f32x4*>(&sca_lds[w][g4 * 4]);
#pragma unroll
      for (int dt = 0; dt < 4; dt++)
#pragma unroll
        for (int r = 0; r < 4; r++) oacc[dt][r] *= sr[r];
    }

    float rs = 0.f;
#pragma unroll
    for (int r = 0; r < 4; r++) {
      s0[r] = __builtin_exp2f(fmaf(s0[r], L2E, -m20));
      s1[r] = __builtin_exp2f(fmaf(s1[r], L2E, -m20));
      rs += s0[r] + s1[r];
    }
    l0 += rs;  // per-lane partial; reduced once in epilogue

    {
      uint2 wv;
      wv.x = pkbf(s0[0], s0[1]); wv.y = pkbf(s0[2], s0[3]);
      *reinterpret_cast<uint2*>(&P_lds[w][r16][g4 * 4]) = wv;
      wv.x = pkbf(s1[0], s1[1]); wv.y = pkbf(s1[2], s1[3]);
      *reinterpret_cast<uint2*>(&P_lds[w][r16][16 + g4 * 4]) = wv;
    }
    short8 pa = *reinterpret_cast<const short8*>(&P_lds[w][r16][g4 * 8]);

    oacc[0] = __builtin_amdgcn_mfma_f32_16x16x32_bf16(pa, v0, oacc[0], 0, 0, 0);
    oacc[1] = __builtin_amdgcn_mfma_f32_16x16x32_bf16(pa, v1, oacc[1], 0, 0, 0);
    oacc[2] = __builtin_amdgcn_mfma_f32_16x16x32_bf16(pa, v2, oacc[2], 0, 0, 0);
    oacc[3] = __builtin_amdgcn_mfma_f32_16x16x32_bf16(pa, v3, oacc[3], 0, 0, 0);

    __syncthreads();  // drains KSTAGE (vmcnt) + protects both LDS buffers
  }
#undef KSTAGE

  // ---- epilogue: reduce per-lane l partials, divide, transpose, store ----
  {
    float rs = l0;
    rs += __shfl_xor(rs, 16);
    rs += __shfl_xor(rs, 32);
    if (g4 == 0) sca_lds[w][r16] = rs;
  }
  f32x4 li = *reinterpret_cast<const f32x4*>(&sca_lds[w][g4 * 4]);
  f32x4 iv;
#pragma unroll
  for (int r = 0; r < 4; r++) iv[r] = 1.f / li[r];
#pragma unroll
  for (int dt = 0; dt < 4; dt++)
#pragma unroll
    for (int r = 0; r < 4; r++)
      Olds[w][g4 * 4 + r][dt * 16 + r16] = oacc[dt][r] * iv[r];
  {
    int orow = lane >> 2, oc = (lane & 3) * 16;
    int bb = bh / NH, h = bh % NH;
    f32x4 a0 = *reinterpret_cast<const f32x4*>(&Olds[w][orow][oc]);
    f32x4 a1 = *reinterpret_cast<const f32x4*>(&Olds[w][orow][oc + 4]);
    f32x4 a2 = *reinterpret_cast<const f32x4*>(&Olds[w][orow][oc + 8]);
    f32x4 a3 = *reinterpret_cast<const f32x4*>(&Olds[w][orow][oc + 12]);
    short8 sa, sb;
#pragma unroll
    for (int j = 0; j < 4; j++) {
      sa[j] = f2bf(a0[j]); sa[4 + j] = f2bf(a1[j]);
      sb[j] = f2bf(a2[j]); sb[4 + j] = f2bf(a3[j]);
    }
    short* dst = &mb[((long)(bb * S_LEN + qw0 + orow)) * EMB + h * HD + oc];
    *reinterpret_cast<short8*>(dst) = sa;
    *reinterpret_cast<short8*>(dst + 8) = sb;
  }
}

extern "C" void kernel_launch(void* const* d_in, const int* in_sizes, int n_in,
                              void* d_out, int out_size, void* d_ws, size_t ws_size,
                              hipStream_t stream) {
  const float* x  = (const float*)d_in[0];
  const float* Wq = (const float*)d_in[1];
  const float* Wk = (const float*)d_in[2];
  const float* Wv = (const float*)d_in[3];
  const float* Wo = (const float*)d_in[4];
  const float* bo = (const float*)d_in[5];

  float* out  = (float*)d_out;
  float* outk = out + 3145728;
  float* outv = out + 6291456;

  short* ws  = (short*)d_ws;
  short* xb  = ws;                 // [4096][768]
  short* Wb  = xb + 3145728;       // [2304][768]  (Wq;Wk;Wv)
  short* Wob = Wb + 1769472;       // [768][768]
  short* qb  = Wob + 589824;       // [24][2048][64]
  short* kb  = qb + 3145728;       // [24][2048][64]
  short* vtb = kb + 3145728;       // [24][64][2048]  (V transposed per head)
  short* mb  = vtb + 3145728;      // [4096][768]    merged attn, bf16

  cvt_bf16<<<3072, 256, 0, stream>>>(x, xb, 3145728);
  cvt_w<<<dim3(576, 4), 256, 0, stream>>>(Wq, Wk, Wv, Wo, Wb, Wob);

  gemm_nt<0><<<dim3(18, 32), 256, 0, stream>>>(xb, Wb, outk, outv, qb, kb, vtb, nullptr, nullptr);
  flash_attn11<<<1536, 128, 0, stream>>>(qb, kb, vtb, mb);
  gemm_nt<1><<<dim3(6, 32), 256, 0, stream>>>(mb, Wob, nullptr, nullptr, nullptr, nullptr, nullptr, out, bo);
}